// Round 14
// baseline (5946.201 us; speedup 1.0000x reference)
//
#include <hip/hip_runtime.h>

#define NN 16384
#define KP1 17
#define EE (NN*16)
#define CAP 448

typedef short bf16x8 __attribute__((ext_vector_type(8)));
typedef float f32x16 __attribute__((ext_vector_type(16)));

__device__ __forceinline__ ushort f2bf(float f) {
  unsigned u = __float_as_uint(f);
  unsigned r = (u + 0x7fffu + ((u >> 16) & 1u)) >> 16;
  return (ushort)r;
}
__device__ __forceinline__ float bf2f(ushort s) { return __uint_as_float(((unsigned)s) << 16); }

// ---------------- h = pos @ W_in + b ----------------
__global__ __launch_bounds__(256) void k_lin_in(const float* __restrict__ pos,
    const float* __restrict__ W, const float* __restrict__ b, float* __restrict__ h) {
  const int t = blockIdx.x*256 + threadIdx.x;
  const int n = t >> 6, c = t & 63;
  float acc = b[c];
  #pragma unroll
  for (int k = 0; k < 11; ++k) acc = fmaf(pos[n*11+k], W[k*64+c], acc);
  h[t] = acc;
}

// ---------------- fused: sq + pk fragments + bf16 hi/lo row planes ----------------
__global__ __launch_bounds__(256) void k_prep_all(const float* __restrict__ h, float* __restrict__ sq,
    ushort* __restrict__ pk, ushort* __restrict__ hbh, ushort* __restrict__ hbl) {
  const int row = blockIdx.x*256 + threadIdx.x;
  const int tile = row >> 5, rl = row & 31;
  const float4* rp = (const float4*)(h + (size_t)row*64);
  float s = 0.f;
  #pragma unroll
  for (int q = 0; q < 16; ++q) {
    const float4 x = rp[q];
    s += x.x*x.x + x.y*x.y + x.z*x.z + x.w*x.w;
    ushort4 hi, lo;
    hi.x = f2bf(x.x); lo.x = f2bf(x.x - bf2f(hi.x));
    hi.y = f2bf(x.y); lo.y = f2bf(x.y - bf2f(hi.y));
    hi.z = f2bf(x.z); lo.z = f2bf(x.z - bf2f(hi.z));
    hi.w = f2bf(x.w); lo.w = f2bf(x.w - bf2f(hi.w));
    *(ushort4*)(hbh + (size_t)row*64 + q*4) = hi;
    *(ushort4*)(hbl + (size_t)row*64 + q*4) = lo;
    const int ks = q >> 2, sub = (q >> 1) & 1, e = (q & 1)*4;
    const int lane = rl + 32*sub;
    ushort* base = pk + (size_t)tile*4096 + ks*1024 + (size_t)lane*8 + e;
    *(ushort4*)(base)       = hi;
    *(ushort4*)(base + 512) = lo;
  }
  sq[row] = s;
}

// ---------------- one-time weight pack ----------------
__global__ __launch_bounds__(256) void k_wprep(const float* __restrict__ W1all,
    const float* __restrict__ W2all, ushort* __restrict__ wp1, ushort* __restrict__ wp2) {
  const int t = blockIdx.x*256 + threadIdx.x;
  if (t < 4096) {
    const int lane = t & 63, ks = (t>>6)&7, mt = (t>>9)&1, l = t>>10;
    const int m = mt*32 + (lane&31);
    const int k0 = ks*16 + (lane>>5)*8;
    const float* w = W1all + l*8192;
    ushort* dst = wp1 + ((((size_t)l*2 + mt)*8 + ks)*2)*512 + (size_t)lane*8;
    #pragma unroll
    for (int e = 0; e < 8; ++e) {
      const float v = w[(k0+e)*64 + m];
      const ushort hi = f2bf(v);
      dst[e] = hi; dst[512+e] = f2bf(v - bf2f(hi));
    }
  } else if (t < 6144) {
    const int t2 = t - 4096;
    const int lane = t2 & 63, ks = (t2>>6)&3, mt = (t2>>8)&1, l = t2>>9;
    const int m = mt*32 + (lane&31);
    const int k0 = ks*16 + (lane>>5)*8;
    const float* w = W2all + l*4096;
    ushort* dst = wp2 + ((((size_t)l*2 + mt)*4 + ks)*2)*512 + (size_t)lane*8;
    #pragma unroll
    for (int e = 0; e < 8; ++e) {
      const float v = w[(k0+e)*64 + m];
      const ushort hi = f2bf(v);
      dst[e] = hi; dst[512+e] = f2bf(v - bf2f(hi));
    }
  }
}

struct F8 { bf16x8 h0,h1,h2,h3,l0,l1,l2,l3; };

__device__ __forceinline__ void ldf(const ushort* __restrict__ pk, int tile, int lane, F8& f) {
  const ushort* tp = pk + (size_t)tile*4096 + (size_t)lane*8;
  f.h0 = *(const bf16x8*)(tp);
  f.l0 = *(const bf16x8*)(tp + 512);
  f.h1 = *(const bf16x8*)(tp + 1024);
  f.l1 = *(const bf16x8*)(tp + 1536);
  f.h2 = *(const bf16x8*)(tp + 2048);
  f.l2 = *(const bf16x8*)(tp + 2560);
  f.h3 = *(const bf16x8*)(tp + 3072);
  f.l3 = *(const bf16x8*)(tp + 3584);
}

#define MF(A,B,C) __builtin_amdgcn_mfma_f32_32x32x16_bf16(A,B,C,0,0,0)

// two candidate tiles, two INDEPENDENT interleaved MFMA chains (R11-proven shape)
__device__ __forceinline__ void tile_keys2(const F8& fa, const F8& fb,
    const bf16x8 (&bqh)[4], const bf16x8 (&bql)[4], const float* __restrict__ sq,
    const int ta, const int tb, const int lhi, float (&ka)[16], float (&kb)[16]) {
  f32x16 a, b;
  #pragma unroll
  for (int i = 0; i < 16; ++i) { a[i] = 0.f; b[i] = 0.f; }
  a = MF(fa.h0, bqh[0], a);  b = MF(fb.h0, bqh[0], b);
  a = MF(fa.h0, bql[0], a);  b = MF(fb.h0, bql[0], b);
  a = MF(fa.l0, bqh[0], a);  b = MF(fb.l0, bqh[0], b);
  a = MF(fa.h1, bqh[1], a);  b = MF(fb.h1, bqh[1], b);
  a = MF(fa.h1, bql[1], a);  b = MF(fb.h1, bql[1], b);
  a = MF(fa.l1, bqh[1], a);  b = MF(fb.l1, bqh[1], b);
  a = MF(fa.h2, bqh[2], a);  b = MF(fb.h2, bqh[2], b);
  a = MF(fa.h2, bql[2], a);  b = MF(fb.h2, bql[2], b);
  a = MF(fa.l2, bqh[2], a);  b = MF(fb.l2, bqh[2], b);
  a = MF(fa.h3, bqh[3], a);  b = MF(fb.h3, bqh[3], b);
  a = MF(fa.h3, bql[3], a);  b = MF(fb.h3, bql[3], b);
  a = MF(fa.l3, bqh[3], a);  b = MF(fb.l3, bqh[3], b);
  const int c0a = ta*32, c0b = tb*32;
  #pragma unroll
  for (int g = 0; g < 4; ++g) {
    const float4 va = *(const float4*)(sq + c0a + g*8 + 4*lhi);
    const float4 vb = *(const float4*)(sq + c0b + g*8 + 4*lhi);
    ka[g*4+0] = fmaf(-2.f, a[g*4+0], va.x);
    ka[g*4+1] = fmaf(-2.f, a[g*4+1], va.y);
    ka[g*4+2] = fmaf(-2.f, a[g*4+2], va.z);
    ka[g*4+3] = fmaf(-2.f, a[g*4+3], va.w);
    kb[g*4+0] = fmaf(-2.f, b[g*4+0], vb.x);
    kb[g*4+1] = fmaf(-2.f, b[g*4+1], vb.y);
    kb[g*4+2] = fmaf(-2.f, b[g*4+2], vb.z);
    kb[g*4+3] = fmaf(-2.f, b[g*4+3], vb.w);
  }
}

#define HIST1(K) { _Pragma("unroll") for (int r = 0; r < 16; ++r) { \
    unsigned x = __float_as_uint(K[r]); x = (x & 0x80000000u) ? ~x : (x | 0x80000000u); \
    atomicAdd(&hist[x >> 24][qcol], 1u); } }
#define HIST2(K) { _Pragma("unroll") for (int r = 0; r < 16; ++r) { \
    unsigned x = __float_as_uint(K[r]); x = (x & 0x80000000u) ? ~x : (x | 0x80000000u); \
    if ((x >> 24) == b1) atomicAdd(&hist[(x >> 16) & 255u][qcol], 1u); } }
#define COLLECT(K, TILE) { _Pragma("unroll") for (int r = 0; r < 16; ++r) { \
    if (K[r] <= bfq) { \
      unsigned x = __float_as_uint(K[r]); x = (x & 0x80000000u) ? ~x : (x | 0x80000000u); \
      const unsigned slot = atomicAdd(&ccnt[qcol], 1u); \
      if (slot < CAP) { \
        const int cidx = (TILE)*32 + (r & 3) + 8*(r >> 2) + 4*lhi; \
        coll[(size_t)q*CAP + slot] = ((unsigned long long)x << 32) | (unsigned)cidx; } } } }

// ---------------- knn: merged bound (1024-subset) + collect, one block per query tile -----
__global__ __launch_bounds__(512) void k_knn(const ushort* __restrict__ pk,
    const float* __restrict__ sq, unsigned long long* __restrict__ coll,
    unsigned* __restrict__ gcnt) {
  __shared__ unsigned hist[256][32];
  __shared__ unsigned part[16][32];
  __shared__ unsigned bin1s[32], below1s[32];
  __shared__ float boundf[32];
  __shared__ unsigned ccnt[32];
  const int tid = threadIdx.x;
  const int wave = tid >> 6, lane = tid & 63;
  const int qcol = lane & 31, lhi = lane >> 5;
  const int qt = blockIdx.x;
  const int q = qt*32 + qcol;

  for (int i = tid; i < 256*32; i += 512) ((unsigned*)hist)[i] = 0u;
  if (tid < 32) ccnt[tid] = 0u;

  bf16x8 bqh[4], bql[4];
  {
    const ushort* tp = pk + (size_t)qt*4096 + (size_t)lane*8;
    #pragma unroll
    for (int ks = 0; ks < 4; ++ks) {
      bqh[ks] = *(const bf16x8*)(tp + ks*1024);
      bql[ks] = *(const bf16x8*)(tp + ks*1024 + 512);
    }
  }
  __syncthreads();

  // phase 1: level-1 hist over subset tiles 0..31 (4 per wave), pairwise interleave
  #pragma unroll 1
  for (int s = 0; s < 4; s += 2) {
    F8 fa, fb;
    ldf(pk, wave*4 + s, lane, fa);
    ldf(pk, wave*4 + s + 1, lane, fb);
    float ka[16], kb[16];
    tile_keys2(fa, fb, bqh, bql, sq, wave*4 + s, wave*4 + s + 1, lhi, ka, kb);
    HIST1(ka)
    HIST1(kb)
  }
  __syncthreads();
  {
    const int qq = tid & 31, j = tid >> 5;
    unsigned ssum = 0;
    #pragma unroll
    for (int i = 0; i < 16; ++i) ssum += hist[j*16 + i][qq];
    part[j][qq] = ssum;
  }
  __syncthreads();
  if (tid < 32) {
    unsigned cum = 0;
    int jj = 0;
    while (jj < 15 && cum + part[jj][tid] < KP1) { cum += part[jj][tid]; ++jj; }
    unsigned c2 = cum, b = 0, fnd = 0;
    #pragma unroll 1
    for (int i = 0; i < 16; ++i) {
      const unsigned nc = c2 + hist[jj*16 + i][tid];
      if (!fnd && nc >= KP1) { b = (unsigned)(jj*16 + i); fnd = 1; break; }
      c2 = nc;
    }
    bin1s[tid] = b; below1s[tid] = c2;
  }
  __syncthreads();
  for (int i = tid; i < 256*32; i += 512) ((unsigned*)hist)[i] = 0u;
  __syncthreads();
  const unsigned b1 = bin1s[qcol];

  // phase 2: level-2 hist within pivot bin (subset tiles 0..31)
  #pragma unroll 1
  for (int s = 0; s < 4; s += 2) {
    F8 fa, fb;
    ldf(pk, wave*4 + s, lane, fa);
    ldf(pk, wave*4 + s + 1, lane, fb);
    float ka[16], kb[16];
    tile_keys2(fa, fb, bqh, bql, sq, wave*4 + s, wave*4 + s + 1, lhi, ka, kb);
    HIST2(ka)
    HIST2(kb)
  }
  __syncthreads();
  {
    const int qq = tid & 31, j = tid >> 5;
    unsigned ssum = 0;
    #pragma unroll
    for (int i = 0; i < 16; ++i) ssum += hist[j*16 + i][qq];
    part[j][qq] = ssum;
  }
  __syncthreads();
  if (tid < 32) {
    unsigned cum = below1s[tid];
    int jj = 0;
    while (jj < 15 && cum + part[jj][tid] < KP1) { cum += part[jj][tid]; ++jj; }
    unsigned c2 = cum, b = 255u, fnd = 0;
    #pragma unroll 1
    for (int i = 0; i < 16; ++i) {
      c2 += hist[jj*16 + i][tid];
      if (!fnd && c2 >= KP1) { b = (unsigned)(jj*16 + i); fnd = 1; }
    }
    const unsigned bu = (bin1s[tid] << 24) | (b << 16) | 0xFFFFu;
    boundf[tid] = __uint_as_float((bu & 0x80000000u) ? (bu & 0x7fffffffu) : ~bu);
  }
  __syncthreads();
  const float bfq = boundf[qcol];

  // phase 3: full scan + collect, 64 tiles/wave, pairwise interleave
  #pragma unroll 1
  for (int s = 0; s < 64; s += 2) {
    F8 fa, fb;
    ldf(pk, wave*64 + s, lane, fa);
    ldf(pk, wave*64 + s + 1, lane, fb);
    float ka[16], kb[16];
    tile_keys2(fa, fb, bqh, bql, sq, wave*64 + s, wave*64 + s + 1, lhi, ka, kb);
    COLLECT(ka, wave*64 + s)
    COLLECT(kb, wave*64 + s + 1)
  }
  __syncthreads();
  if (tid < 32) gcnt[qt*32 + tid] = min(ccnt[tid], (unsigned)CAP);
}

// ---------------- select: one wave per query, exact top-17; fused cnt[to]++ ----------------
__global__ __launch_bounds__(256) void k_select(const unsigned long long* __restrict__ coll,
    const unsigned* __restrict__ gcnt, int* __restrict__ idxout, unsigned* __restrict__ cnt) {
  const int gw = (blockIdx.x*256 + threadIdx.x) >> 6;
  const int lane = threadIdx.x & 63;
  const int m = min((int)gcnt[gw], CAP);
  const unsigned long long* cp = coll + (size_t)gw*CAP;
  unsigned long long a0,a1,a2,a3,a4,a5,a6;
  a0 = (lane       < m) ? cp[lane      ] : ~0ULL;
  a1 = (lane +  64 < m) ? cp[lane +  64] : ~0ULL;
  a2 = (lane + 128 < m) ? cp[lane + 128] : ~0ULL;
  a3 = (lane + 192 < m) ? cp[lane + 192] : ~0ULL;
  a4 = (lane + 256 < m) ? cp[lane + 256] : ~0ULL;
  a5 = (lane + 320 < m) ? cp[lane + 320] : ~0ULL;
  a6 = (lane + 384 < m) ? cp[lane + 384] : ~0ULL;
  #define CS(X,Y) { if (Y < X) { const unsigned long long t_ = X; X = Y; Y = t_; } }
  CS(a0,a1) CS(a2,a3) CS(a4,a5)
  CS(a1,a2) CS(a3,a4) CS(a5,a6)
  CS(a0,a1) CS(a2,a3) CS(a4,a5)
  CS(a1,a2) CS(a3,a4) CS(a5,a6)
  CS(a0,a1) CS(a2,a3) CS(a4,a5)
  CS(a1,a2) CS(a3,a4) CS(a5,a6)
  CS(a0,a1) CS(a2,a3) CS(a4,a5)
  #undef CS
  #pragma unroll
  for (int p = 0; p < KP1; ++p) {
    unsigned long long w = a0;
    #pragma unroll
    for (int d = 1; d < 64; d <<= 1) {
      const unsigned long long o = __shfl_xor(w, d);
      w = o < w ? o : w;
    }
    if (lane == 0) {
      const int ni = (int)(unsigned)(w & 0xffffffffULL);
      idxout[gw*KP1 + p] = ni;
      if (p > 0) atomicAdd(&cnt[ni], 1u);
    }
    if (a0 == w) { a0=a1; a1=a2; a2=a3; a3=a4; a4=a5; a5=a6; a6=~0ULL; }
  }
}

// ---------------- prefix scan of cnt -> offs/pos ----------------
__global__ __launch_bounds__(256) void k_scan(const unsigned* __restrict__ cnt,
    unsigned* __restrict__ offs, unsigned* __restrict__ pos) {
  __shared__ unsigned ps[256];
  const int t = threadIdx.x;
  unsigned s = 0;
  #pragma unroll 4
  for (int j = 0; j < 64; ++j) s += cnt[t*64 + j];
  ps[t] = s;
  __syncthreads();
  for (int d = 1; d < 256; d <<= 1) {
    const unsigned v = (t >= d) ? ps[t-d] : 0u;
    __syncthreads();
    ps[t] += v;
    __syncthreads();
  }
  unsigned run = ps[t] - s;
  #pragma unroll 4
  for (int j = 0; j < 64; ++j) {
    const unsigned c = cnt[t*64 + j];
    offs[t*64 + j] = run; pos[t*64 + j] = run;
    run += c;
  }
}

__global__ __launch_bounds__(256) void k_scatter(const int* __restrict__ idx,
    unsigned* __restrict__ pos, unsigned* __restrict__ sortedE) {
  const int e = blockIdx.x*256 + threadIdx.x;
  const int i = e & (NN-1), k = e >> 14;
  const int to = idx[i*KP1 + k + 1];
  sortedE[atomicAdd(&pos[to], 1u)] = (unsigned)e;
}

// gather-reduce: thread per (node, 16B chunk); applies BN+ReLU to y2 then sums
__global__ __launch_bounds__(256) void k_agg(const ushort* __restrict__ y2,
    const unsigned* __restrict__ offs, const unsigned* __restrict__ cnt,
    const unsigned* __restrict__ sortedE,
    const float* __restrict__ s, const float* __restrict__ s2,
    const float* __restrict__ gam, const float* __restrict__ bet, float* __restrict__ agg) {
  __shared__ float scs[64], shs[64];
  const int tid = threadIdx.x;
  if (tid < 64) {
    const float m = s[tid] * (1.f/(float)EE);
    const float v = fmaxf(s2[tid]*(1.f/(float)EE) - m*m, 0.f);
    const float scv = gam[tid]*rsqrtf(v + 1e-5f);
    scs[tid] = scv; shs[tid] = bet[tid] - m*scv;
  }
  __syncthreads();
  const int t = blockIdx.x*256 + tid;
  const int n = t >> 4, c4 = t & 15;
  const unsigned o = offs[n], m = cnt[n];
  const float sc0 = scs[c4*4+0], sc1 = scs[c4*4+1], sc2 = scs[c4*4+2], sc3 = scs[c4*4+3];
  const float sh0 = shs[c4*4+0], sh1 = shs[c4*4+1], sh2 = shs[c4*4+2], sh3 = shs[c4*4+3];
  float a0=0.f, a1=0.f, a2=0.f, a3=0.f;
  for (unsigned j = 0; j < m; ++j) {
    const unsigned e = sortedE[o + j];
    const ushort4 v = *(const ushort4*)(y2 + (size_t)e*64 + c4*4);
    a0 += fmaxf(fmaf(bf2f(v.x), sc0, sh0), 0.f);
    a1 += fmaxf(fmaf(bf2f(v.y), sc1, sh1), 0.f);
    a2 += fmaxf(fmaf(bf2f(v.z), sc2, sh2), 0.f);
    a3 += fmaxf(fmaf(bf2f(v.w), sc3, sh3), 0.f);
  }
  *(float4*)(agg + (size_t)n*64 + c4*4) = make_float4(a0, a1, a2, a3);
}

// ---------------- edge linear-1 (MFMA) + fused column stats ----------------
__global__ __launch_bounds__(256) void k_eA(const ushort* __restrict__ hbh,
    const ushort* __restrict__ hbl, const int* __restrict__ idx,
    const ushort* __restrict__ wp1, const float* __restrict__ b1, ushort* __restrict__ y1,
    float* __restrict__ sst, float* __restrict__ s2st) {
  __shared__ ushort wlds[16384];
  __shared__ float b1s[64];
  __shared__ ushort ytr[4][32][40];
  const int tid = threadIdx.x, wave = tid >> 6, lane = tid & 63;
  const int n = lane & 31, lhi = lane >> 5;
  for (int i = tid*8; i < 16384; i += 2048) *(uint4*)(wlds+i) = *(const uint4*)(wp1+i);
  if (tid < 64) b1s[tid] = b1[tid];
  __syncthreads();

  const int tile = blockIdx.x*4 + wave;
  const int e = tile*32 + n;
  const int i_ = e & (NN-1), kk = e >> 14;
  const int to = idx[i_*KP1 + kk + 1];
  const int fr = idx[i_*KP1];

  bf16x8 bh[8], bl[8];
  #pragma unroll
  for (int ks = 0; ks < 4; ++ks) {
    const size_t off = (size_t)to*64 + ks*16 + lhi*8;
    bh[ks] = *(const bf16x8*)(hbh + off);
    bl[ks] = *(const bf16x8*)(hbl + off);
  }
  #pragma unroll
  for (int ks = 0; ks < 4; ++ks) {
    const size_t off = (size_t)fr*64 + ks*16 + lhi*8;
    bh[4+ks] = *(const bf16x8*)(hbh + off);
    bl[4+ks] = *(const bf16x8*)(hbl + off);
  }

  f32x16 aA[2], aB[2];
  #pragma unroll
  for (int i = 0; i < 16; ++i) { aA[0][i]=0.f; aA[1][i]=0.f; aB[0][i]=0.f; aB[1][i]=0.f; }
  #pragma unroll
  for (int mt = 0; mt < 2; ++mt) {
    #pragma unroll
    for (int ks = 0; ks < 8; ++ks) {
      const ushort* wp = wlds + ((mt*8+ks)*2)*512 + lane*8;
      const bf16x8 wh = *(const bf16x8*)wp;
      const bf16x8 wl = *(const bf16x8*)(wp + 512);
      aA[mt] = MF(wh, bh[ks], aA[mt]);
      aB[mt] = MF(wh, bl[ks], aB[mt]);
      aB[mt] = MF(wl, bh[ks], aB[mt]);
    }
  }

  #pragma unroll
  for (int mt = 0; mt < 2; ++mt) {
    #pragma unroll
    for (int g = 0; g < 4; ++g) {
      const int mb = mt*32 + g*8 + lhi*4;
      ushort4 p;
      p.x = f2bf(aA[mt][g*4+0] + aB[mt][g*4+0] + b1s[mb+0]);
      p.y = f2bf(aA[mt][g*4+1] + aB[mt][g*4+1] + b1s[mb+1]);
      p.z = f2bf(aA[mt][g*4+2] + aB[mt][g*4+2] + b1s[mb+2]);
      p.w = f2bf(aA[mt][g*4+3] + aB[mt][g*4+3] + b1s[mb+3]);
      *(ushort4*)(&ytr[wave][n][g*8 + lhi*4]) = p;
    }
    __syncthreads();
    #pragma unroll
    for (int rep = 0; rep < 2; ++rep) {
      const int s = rep*256 + tid;
      const int w = s >> 7, inner = s & 127;
      const int nn = inner >> 2, c8 = inner & 3;
      const bf16x8 v = *(const bf16x8*)(&ytr[w][nn][c8*8]);
      const int tw = blockIdx.x*4 + w;
      *(bf16x8*)(y1 + ((size_t)tw*32 + nn)*64 + mt*32 + c8*8) = v;
    }
    // fused column stats for this mt's 32 columns (4 waves x 32 rows each)
    if (tid < 128) {
      const int w = tid >> 5, c = tid & 31;
      float sum = 0.f, sq_ = 0.f;
      #pragma unroll
      for (int nn = 0; nn < 32; ++nn) {
        const float v = bf2f(ytr[w][nn][c]);
        sum += v; sq_ = fmaf(v, v, sq_);
      }
      atomicAdd(&sst[mt*32 + c], sum);
      atomicAdd(&s2st[mt*32 + c], sq_);
    }
    __syncthreads();
  }
}

// ---------------- edge linear-2 (MFMA) + fused column stats ----------------
__global__ __launch_bounds__(256) void k_eB(const ushort* __restrict__ y1,
    const float* __restrict__ s, const float* __restrict__ s2,
    const float* __restrict__ gam, const float* __restrict__ bet,
    const ushort* __restrict__ wp2, const float* __restrict__ b2, ushort* __restrict__ y2,
    float* __restrict__ sst, float* __restrict__ s2st) {
  __shared__ ushort wlds[8192];
  __shared__ float scs[64], shs[64], b2s[64];
  __shared__ ushort ytr[4][32][40];
  const int tid = threadIdx.x, wave = tid >> 6, lane = tid & 63;
  const int n = lane & 31, lhi = lane >> 5;
  for (int i = tid*8; i < 8192; i += 2048) *(uint4*)(wlds+i) = *(const uint4*)(wp2+i);
  if (tid < 64) {
    const float m = s[tid] * (1.f/(float)EE);
    const float v = fmaxf(s2[tid]*(1.f/(float)EE) - m*m, 0.f);
    const float scv = gam[tid]*rsqrtf(v + 1e-5f);
    scs[tid] = scv; shs[tid] = bet[tid] - m*scv; b2s[tid] = b2[tid];
  }
  __syncthreads();

  const int tile = blockIdx.x*4 + wave;
  const int e = tile*32 + n;

  bf16x8 bh[4], bl[4];
  #pragma unroll
  for (int ks = 0; ks < 4; ++ks) {
    const ushort4 v0 = *(const ushort4*)(y1 + (size_t)e*64 + ks*16 + lhi*8);
    const ushort4 v1 = *(const ushort4*)(y1 + (size_t)e*64 + ks*16 + lhi*8 + 4);
    const int k0 = ks*16 + lhi*8;
    float x[8];
    x[0]=bf2f(v0.x); x[1]=bf2f(v0.y); x[2]=bf2f(v0.z); x[3]=bf2f(v0.w);
    x[4]=bf2f(v1.x); x[5]=bf2f(v1.y); x[6]=bf2f(v1.z); x[7]=bf2f(v1.w);
    #pragma unroll
    for (int j = 0; j < 8; ++j) {
      const float f = fmaxf(fmaf(x[j], scs[k0+j], shs[k0+j]), 0.f);
      const ushort hi = f2bf(f);
      bh[ks][j] = (short)hi;
      bl[ks][j] = (short)f2bf(f - bf2f(hi));
    }
  }

  f32x16 aA[2], aB[2];
  #pragma unroll
  for (int i = 0; i < 16; ++i) { aA[0][i]=0.f; aA[1][i]=0.f; aB[0][i]=0.f; aB[1][i]=0.f; }
  #pragma unroll
  for (int mt = 0; mt < 2; ++mt) {
    #pragma unroll
    for (int ks = 0; ks < 4; ++ks) {
      const ushort* wp = wlds + ((mt*4+ks)*2)*512 + lane*8;
      const bf16x8 wh = *(const bf16x8*)wp;
      const bf16x8 wl = *(const bf16x8*)(wp + 512);
      aA[mt] = MF(wh, bh[ks], aA[mt]);
      aB[mt] = MF(wh, bl[ks], aB[mt]);
      aB[mt] = MF(wl, bh[ks], aB[mt]);
    }
  }

  #pragma unroll
  for (int mt = 0; mt < 2; ++mt) {
    #pragma unroll
    for (int g = 0; g < 4; ++g) {
      const int mb = mt*32 + g*8 + lhi*4;
      ushort4 p;
      p.x = f2bf(aA[mt][g*4+0] + aB[mt][g*4+0] + b2s[mb+0]);
      p.y = f2bf(aA[mt][g*4+1] + aB[mt][g*4+1] + b2s[mb+1]);
      p.z = f2bf(aA[mt][g*4+2] + aB[mt][g*4+2] + b2s[mb+2]);
      p.w = f2bf(aA[mt][g*4+3] + aB[mt][g*4+3] + b2s[mb+3]);
      *(ushort4*)(&ytr[wave][n][g*8 + lhi*4]) = p;
    }
    __syncthreads();
    #pragma unroll
    for (int rep = 0; rep < 2; ++rep) {
      const int ss = rep*256 + tid;
      const int w = ss >> 7, inner = ss & 127;
      const int nn = inner >> 2, c8 = inner & 3;
      const bf16x8 v = *(const bf16x8*)(&ytr[w][nn][c8*8]);
      const int tw = blockIdx.x*4 + w;
      *(bf16x8*)(y2 + ((size_t)tw*32 + nn)*64 + mt*32 + c8*8) = v;
    }
    if (tid < 128) {
      const int w = tid >> 5, c = tid & 31;
      float sum = 0.f, sq_ = 0.f;
      #pragma unroll
      for (int nn = 0; nn < 32; ++nn) {
        const float v = bf2f(ytr[w][nn][c]);
        sum += v; sq_ = fmaf(v, v, sq_);
      }
      atomicAdd(&sst[mt*32 + c], sum);
      atomicAdd(&s2st[mt*32 + c], sq_);
    }
    __syncthreads();
  }
}

// ---------------- fp32 column stats (upd path) ----------------
__global__ __launch_bounds__(256) void k_colstats(const float* __restrict__ x, const int rows,
    float* __restrict__ s, float* __restrict__ s2) {
  __shared__ float ls[4][64], ls2[4][64];
  const int tid = threadIdx.x;
  const int c = tid & 63, g = tid >> 6;
  float a = 0.f, b = 0.f;
  for (int r = blockIdx.x*4 + g; r < rows; r += 1024) {
    const float v = x[(size_t)r*64 + c];
    a += v; b = fmaf(v, v, b);
  }
  ls[g][c] = a; ls2[g][c] = b;
  __syncthreads();
  if (tid < 64) {
    atomicAdd(&s[tid],  ls[0][tid]+ls[1][tid]+ls[2][tid]+ls[3][tid]);
    atomicAdd(&s2[tid], ls2[0][tid]+ls2[1][tid]+ls2[2][tid]+ls2[3][tid]);
  }
}

__device__ __forceinline__ void fmarow(float (&acc)[64], const float (*ws)[64], int kk, float xv) {
  #pragma unroll
  for (int cq = 0; cq < 16; ++cq) {
    const float4 w4 = *(const float4*)&ws[kk][cq*4];
    acc[cq*4]   = fmaf(xv, w4.x, acc[cq*4]);
    acc[cq*4+1] = fmaf(xv, w4.y, acc[cq*4+1]);
    acc[cq*4+2] = fmaf(xv, w4.z, acc[cq*4+2]);
    acc[cq*4+3] = fmaf(xv, w4.w, acc[cq*4+3]);
  }
}

// ---------------- upd linear-1: ubuf = [h | agg] @ W1 + b1 (fp32) ----------------
__global__ __launch_bounds__(256) void k_mlpA_cat(const float* __restrict__ h,
    const float* __restrict__ agg, const float* __restrict__ W1, const float* __restrict__ b1,
    float* __restrict__ y) {
  __shared__ __align__(16) float ws[128][64];
  const int tid = threadIdx.x;
  for (int t = tid; t < 128*64/4; t += 256) ((float4*)ws)[t] = ((const float4*)W1)[t];
  __syncthreads();
  const int n = blockIdx.x*256 + tid;
  float acc[64];
  #pragma unroll
  for (int c = 0; c < 64; ++c) acc[c] = b1[c];
  const float4* xa = (const float4*)(h + (size_t)n*64);
  #pragma unroll 2
  for (int kb = 0; kb < 16; ++kb) {
    const float4 x4 = xa[kb];
    fmarow(acc, ws, kb*4,   x4.x); fmarow(acc, ws, kb*4+1, x4.y);
    fmarow(acc, ws, kb*4+2, x4.z); fmarow(acc, ws, kb*4+3, x4.w);
  }
  const float4* xb = (const float4*)(agg + (size_t)n*64);
  #pragma unroll 2
  for (int kb = 0; kb < 16; ++kb) {
    const float4 x4 = xb[kb];
    fmarow(acc, ws, 64+kb*4,   x4.x); fmarow(acc, ws, 64+kb*4+1, x4.y);
    fmarow(acc, ws, 64+kb*4+2, x4.z); fmarow(acc, ws, 64+kb*4+3, x4.w);
  }
  float4* yo = (float4*)(y + (size_t)n*64);
  #pragma unroll
  for (int q = 0; q < 16; ++q) yo[q] = make_float4(acc[4*q], acc[4*q+1], acc[4*q+2], acc[4*q+3]);
}

// ---------------- upd linear-2 with fused BN+ReLU, in-place (fp32) ----------------
__global__ __launch_bounds__(256) void k_mlpB(float* __restrict__ y,
    const float* __restrict__ s, const float* __restrict__ s2,
    const float* __restrict__ g, const float* __restrict__ be,
    const float* __restrict__ W2, const float* __restrict__ b2, const float invR) {
  __shared__ __align__(16) float ws[64][64];
  __shared__ float sc[64], sh[64];
  const int tid = threadIdx.x;
  for (int t = tid; t < 64*64/4; t += 256) ((float4*)ws)[t] = ((const float4*)W2)[t];
  if (tid < 64) {
    const float m = s[tid]*invR;
    const float v = fmaxf(s2[tid]*invR - m*m, 0.f);
    const float scv = g[tid]*rsqrtf(v + 1e-5f);
    sc[tid] = scv; sh[tid] = be[tid] - m*scv;
  }
  __syncthreads();
  const int e = blockIdx.x*256 + tid;
  float acc[64];
  #pragma unroll
  for (int c = 0; c < 64; ++c) acc[c] = b2[c];
  const float4* yr = (const float4*)(y + (size_t)e*64);
  #pragma unroll 2
  for (int kb = 0; kb < 16; ++kb) {
    const float4 x4 = yr[kb];
    const int k0 = kb*4;
    fmarow(acc, ws, k0,   fmaxf(fmaf(x4.x, sc[k0],   sh[k0]),   0.f));
    fmarow(acc, ws, k0+1, fmaxf(fmaf(x4.y, sc[k0+1], sh[k0+1]), 0.f));
    fmarow(acc, ws, k0+2, fmaxf(fmaf(x4.z, sc[k0+2], sh[k0+2]), 0.f));
    fmarow(acc, ws, k0+3, fmaxf(fmaf(x4.w, sc[k0+3], sh[k0+3]), 0.f));
  }
  float4* yo = (float4*)(y + (size_t)e*64);
  #pragma unroll
  for (int q = 0; q < 16; ++q) yo[q] = make_float4(acc[4*q], acc[4*q+1], acc[4*q+2], acc[4*q+3]);
}

// ---------------- upd final BN+ReLU + residual (layer 3 only) ----------------
__global__ __launch_bounds__(256) void k_updC(const float* __restrict__ y,
    const float* __restrict__ s, const float* __restrict__ s2,
    const float* __restrict__ g, const float* __restrict__ be,
    float* __restrict__ h, const float invR) {
  __shared__ float sc[64], sh[64];
  const int tid = threadIdx.x;
  if (tid < 64) {
    const float m = s[tid]*invR;
    const float v = fmaxf(s2[tid]*invR - m*m, 0.f);
    const float scv = g[tid]*rsqrtf(v + 1e-5f);
    sc[tid] = scv; sh[tid] = be[tid] - m*scv;
  }
  __syncthreads();
  const int t = blockIdx.x*256 + tid;
  const int c = t & 63;
  h[t] += fmaxf(fmaf(y[t], sc[c], sh[c]), 0.f);
}

// ---------------- fused: updC + next-layer prep (layers 0..2) ----------------
__global__ __launch_bounds__(256) void k_updC_prep(const float* __restrict__ y,
    const float* __restrict__ s, const float* __restrict__ s2,
    const float* __restrict__ g, const float* __restrict__ be,
    float* __restrict__ h, const float invR,
    float* __restrict__ sq, ushort* __restrict__ pk,
    ushort* __restrict__ hbh, ushort* __restrict__ hbl) {
  __shared__ float sc[64], sh[64];
  const int tid = threadIdx.x;
  if (tid < 64) {
    const float m = s[tid]*invR;
    const float v = fmaxf(s2[tid]*invR - m*m, 0.f);
    const float scv = g[tid]*rsqrtf(v + 1e-5f);
    sc[tid] = scv; sh[tid] = be[tid] - m*scv;
  }
  __syncthreads();
  const int row = blockIdx.x*256 + tid;
  const int tile = row >> 5, rl = row & 31;
  float4* hp = (float4*)(h + (size_t)row*64);
  const float4* yp = (const float4*)(y + (size_t)row*64);
  float ssum = 0.f;
  #pragma unroll
  for (int q = 0; q < 16; ++q) {
    const float4 yv = yp[q];
    float4 x = hp[q];
    const int k0 = q*4;
    x.x += fmaxf(fmaf(yv.x, sc[k0+0], sh[k0+0]), 0.f);
    x.y += fmaxf(fmaf(yv.y, sc[k0+1], sh[k0+1]), 0.f);
    x.z += fmaxf(fmaf(yv.z, sc[k0+2], sh[k0+2]), 0.f);
    x.w += fmaxf(fmaf(yv.w, sc[k0+3], sh[k0+3]), 0.f);
    hp[q] = x;
    ssum += x.x*x.x + x.y*x.y + x.z*x.z + x.w*x.w;
    ushort4 hi, lo;
    hi.x = f2bf(x.x); lo.x = f2bf(x.x - bf2f(hi.x));
    hi.y = f2bf(x.y); lo.y = f2bf(x.y - bf2f(hi.y));
    hi.z = f2bf(x.z); lo.z = f2bf(x.z - bf2f(hi.z));
    hi.w = f2bf(x.w); lo.w = f2bf(x.w - bf2f(hi.w));
    *(ushort4*)(hbh + (size_t)row*64 + q*4) = hi;
    *(ushort4*)(hbl + (size_t)row*64 + q*4) = lo;
    const int ks = q >> 2, sub = (q >> 1) & 1, e = (q & 1)*4;
    const int lane = rl + 32*sub;
    ushort* base = pk + (size_t)tile*4096 + ks*1024 + (size_t)lane*8 + e;
    *(ushort4*)(base)       = hi;
    *(ushort4*)(base + 512) = lo;
  }
  sq[row] = ssum;
}

// ---------------- out = mean(h) @ predW + predb ----------------
__global__ void k_final(const float* __restrict__ hsum, const float* __restrict__ pW,
                        const float* __restrict__ pb, float* __restrict__ out) {
  const int c = threadIdx.x;
  float v = hsum[c] * (1.f/(float)NN) * pW[c];
  #pragma unroll
  for (int m = 32; m >= 1; m >>= 1) v += __shfl_xor(v, m, 64);
  if (c == 0) out[0] = v + pb[0];
}

extern "C" void kernel_launch(void* const* d_in, const int* in_sizes, int n_in,
                              void* d_out, int out_size, void* d_ws, size_t ws_size,
                              hipStream_t stream) {
  const float* pos   = (const float*)d_in[0];
  const float* linW  = (const float*)d_in[1];
  const float* linb  = (const float*)d_in[2];
  const float* predW = (const float*)d_in[3];
  const float* predb = (const float*)d_in[4];
  const float* mW1 = (const float*)d_in[5];
  const float* mb1 = (const float*)d_in[6];
  const float* mg1 = (const float*)d_in[7];
  const float* mbe1= (const float*)d_in[8];
  const float* mW2 = (const float*)d_in[9];
  const float* mb2 = (const float*)d_in[10];
  const float* mg2 = (const float*)d_in[11];
  const float* mbe2= (const float*)d_in[12];
  const float* uW1 = (const float*)d_in[13];
  const float* ub1 = (const float*)d_in[14];
  const float* ug1 = (const float*)d_in[15];
  const float* ube1= (const float*)d_in[16];
  const float* uW2 = (const float*)d_in[17];
  const float* ub2 = (const float*)d_in[18];
  const float* ug2 = (const float*)d_in[19];
  const float* ube2= (const float*)d_in[20];

  // workspace layout (~81.3 MB)
  float* h     = (float*)d_ws;                    // N*64
  float* sq    = h + (size_t)NN*64;               // N
  float* agg   = sq + NN;                         // N*64
  float* ubuf  = agg + (size_t)NN*64;             // N*64 (4 MB; also scratch below)
  float* stats = ubuf + (size_t)NN*64;            // 640
  int*   idx   = (int*)(stats + 640);             // N*17
  char*  yb    = (char*)(idx + (size_t)NN*KP1);   // 67.3 MB region
  ushort* pk = (ushort*)yb;                                        // 4.19 MB
  unsigned long long* coll = (unsigned long long*)(yb + 4194304);  // 58.72 MB
  ushort* hbh = (ushort*)(yb + 62914560);                          // 2 MB
  ushort* hbl = hbh + (size_t)NN*64;                               // 2 MB
  ushort* y1 = (ushort*)yb;                                        // EE*64 bf16 = 33.5 MB
  ushort* y2 = y1 + (size_t)EE*64;                                 // 33.5 MB
  ushort* wp1 = (ushort*)(yb + 67108864);                          // 128 KB
  ushort* wp2 = wp1 + 4*16384;                                     // 64 KB
  unsigned* cnt     = (unsigned*)ubuf;            // NN
  unsigned* offs    = cnt + NN;                   // NN
  unsigned* pcur    = offs + NN;                  // NN
  unsigned* sortedE = pcur + NN;                  // EE
  unsigned* gcnt    = sortedE + EE;               // NN (k_knn writes all entries; no memset)

  k_lin_in<<<NN*64/256, 256, 0, stream>>>(pos, linW, linb, h);
  k_wprep<<<24, 256, 0, stream>>>(mW1, mW2, wp1, wp2);
  k_prep_all<<<NN/256, 256, 0, stream>>>(h, sq, pk, hbh, hbl);
  for (int l = 0; l < 4; ++l) {
    k_knn<<<NN/32, 512, 0, stream>>>(pk, sq, coll, gcnt);
    hipMemsetAsync(cnt, 0, NN*sizeof(unsigned), stream);
    k_select<<<NN/4, 256, 0, stream>>>(coll, gcnt, idx, cnt);
    hipMemsetAsync(stats, 0, 640*sizeof(float), stream);
    k_scan<<<1, 256, 0, stream>>>(cnt, offs, pcur);
    k_scatter<<<EE/256, 256, 0, stream>>>(idx, pcur, sortedE);
    // edge MLP (MFMA) over E edges, stats fused
    k_eA<<<EE/32/4, 256, 0, stream>>>(hbh, hbl, idx, wp1 + (size_t)l*16384, mb1 + l*64, y1,
                                      stats, stats+64);
    k_eB<<<EE/32/4, 256, 0, stream>>>(y1, stats, stats+64, mg1 + l*64, mbe1 + l*64,
                                      wp2 + (size_t)l*8192, mb2 + l*64, y2,
                                      stats+128, stats+192);
    k_agg<<<NN*16/256, 256, 0, stream>>>(y2, offs, cnt, sortedE, stats+128, stats+192,
                                         mg2 + l*64, mbe2 + l*64, agg);
    // upd MLP over N nodes (fp32)
    k_mlpA_cat<<<NN/256, 256, 0, stream>>>(h, agg, uW1 + l*8192, ub1 + l*64, ubuf);
    k_colstats<<<256, 256, 0, stream>>>(ubuf, NN, stats+256, stats+320);
    k_mlpB<<<NN/256, 256, 0, stream>>>(ubuf, stats+256, stats+320, ug1 + l*64, ube1 + l*64,
                                       uW2 + l*4096, ub2 + l*64, 1.f/(float)NN);
    k_colstats<<<256, 256, 0, stream>>>(ubuf, NN, stats+384, stats+448);
    if (l < 3) {
      k_updC_prep<<<NN/256, 256, 0, stream>>>(ubuf, stats+384, stats+448, ug2 + l*64, ube2 + l*64,
                                              h, 1.f/(float)NN, sq, pk, hbh, hbl);
    } else {
      k_updC<<<NN*64/256, 256, 0, stream>>>(ubuf, stats+384, stats+448, ug2 + l*64, ube2 + l*64,
                                            h, 1.f/(float)NN);
    }
  }
  hipMemsetAsync(stats+512, 0, 128*sizeof(float), stream);
  k_colstats<<<256, 256, 0, stream>>>(h, NN, stats+512, stats+576);
  k_final<<<1, 64, 0, stream>>>(stats+512, predW, predb, (float*)d_out);
}

// Round 15
// 2267.224 us; speedup vs baseline: 2.6227x; 2.6227x over previous
//
#include <hip/hip_runtime.h>

#define NN 16384
#define KP1 17
#define EE (NN*16)
#define CAP 448

typedef short bf16x8 __attribute__((ext_vector_type(8)));
typedef float f32x16 __attribute__((ext_vector_type(16)));

__device__ __forceinline__ ushort f2bf(float f) {
  unsigned u = __float_as_uint(f);
  unsigned r = (u + 0x7fffu + ((u >> 16) & 1u)) >> 16;
  return (ushort)r;
}
__device__ __forceinline__ float bf2f(ushort s) { return __uint_as_float(((unsigned)s) << 16); }

// ---------------- h = pos @ W_in + b ----------------
__global__ __launch_bounds__(256) void k_lin_in(const float* __restrict__ pos,
    const float* __restrict__ W, const float* __restrict__ b, float* __restrict__ h) {
  const int t = blockIdx.x*256 + threadIdx.x;
  const int n = t >> 6, c = t & 63;
  float acc = b[c];
  #pragma unroll
  for (int k = 0; k < 11; ++k) acc = fmaf(pos[n*11+k], W[k*64+c], acc);
  h[t] = acc;
}

// ---------------- fused: sq + pk fragments + bf16 hi/lo row planes ----------------
__global__ __launch_bounds__(256) void k_prep_all(const float* __restrict__ h, float* __restrict__ sq,
    ushort* __restrict__ pk, ushort* __restrict__ hbh, ushort* __restrict__ hbl) {
  const int row = blockIdx.x*256 + threadIdx.x;
  const int tile = row >> 5, rl = row & 31;
  const float4* rp = (const float4*)(h + (size_t)row*64);
  float s = 0.f;
  #pragma unroll
  for (int q = 0; q < 16; ++q) {
    const float4 x = rp[q];
    s += x.x*x.x + x.y*x.y + x.z*x.z + x.w*x.w;
    ushort4 hi, lo;
    hi.x = f2bf(x.x); lo.x = f2bf(x.x - bf2f(hi.x));
    hi.y = f2bf(x.y); lo.y = f2bf(x.y - bf2f(hi.y));
    hi.z = f2bf(x.z); lo.z = f2bf(x.z - bf2f(hi.z));
    hi.w = f2bf(x.w); lo.w = f2bf(x.w - bf2f(hi.w));
    *(ushort4*)(hbh + (size_t)row*64 + q*4) = hi;
    *(ushort4*)(hbl + (size_t)row*64 + q*4) = lo;
    const int ks = q >> 2, sub = (q >> 1) & 1, e = (q & 1)*4;
    const int lane = rl + 32*sub;
    ushort* base = pk + (size_t)tile*4096 + ks*1024 + (size_t)lane*8 + e;
    *(ushort4*)(base)       = hi;
    *(ushort4*)(base + 512) = lo;
  }
  sq[row] = s;
}

// ---------------- one-time weight pack ----------------
__global__ __launch_bounds__(256) void k_wprep(const float* __restrict__ W1all,
    const float* __restrict__ W2all, ushort* __restrict__ wp1, ushort* __restrict__ wp2) {
  const int t = blockIdx.x*256 + threadIdx.x;
  if (t < 4096) {
    const int lane = t & 63, ks = (t>>6)&7, mt = (t>>9)&1, l = t>>10;
    const int m = mt*32 + (lane&31);
    const int k0 = ks*16 + (lane>>5)*8;
    const float* w = W1all + l*8192;
    ushort* dst = wp1 + ((((size_t)l*2 + mt)*8 + ks)*2)*512 + (size_t)lane*8;
    #pragma unroll
    for (int e = 0; e < 8; ++e) {
      const float v = w[(k0+e)*64 + m];
      const ushort hi = f2bf(v);
      dst[e] = hi; dst[512+e] = f2bf(v - bf2f(hi));
    }
  } else if (t < 6144) {
    const int t2 = t - 4096;
    const int lane = t2 & 63, ks = (t2>>6)&3, mt = (t2>>8)&1, l = t2>>9;
    const int m = mt*32 + (lane&31);
    const int k0 = ks*16 + (lane>>5)*8;
    const float* w = W2all + l*4096;
    ushort* dst = wp2 + ((((size_t)l*2 + mt)*4 + ks)*2)*512 + (size_t)lane*8;
    #pragma unroll
    for (int e = 0; e < 8; ++e) {
      const float v = w[(k0+e)*64 + m];
      const ushort hi = f2bf(v);
      dst[e] = hi; dst[512+e] = f2bf(v - bf2f(hi));
    }
  }
}

struct F8 { bf16x8 h0,h1,h2,h3,l0,l1,l2,l3; };

__device__ __forceinline__ void ldf(const ushort* __restrict__ pk, int tile, int lane, F8& f) {
  const ushort* tp = pk + (size_t)tile*4096 + (size_t)lane*8;
  f.h0 = *(const bf16x8*)(tp);
  f.l0 = *(const bf16x8*)(tp + 512);
  f.h1 = *(const bf16x8*)(tp + 1024);
  f.l1 = *(const bf16x8*)(tp + 1536);
  f.h2 = *(const bf16x8*)(tp + 2048);
  f.l2 = *(const bf16x8*)(tp + 2560);
  f.h3 = *(const bf16x8*)(tp + 3072);
  f.l3 = *(const bf16x8*)(tp + 3584);
}

#define MF(A,B,C) __builtin_amdgcn_mfma_f32_32x32x16_bf16(A,B,C,0,0,0)

// two candidate tiles, two INDEPENDENT interleaved MFMA chains (R11-proven shape)
__device__ __forceinline__ void tile_keys2(const F8& fa, const F8& fb,
    const bf16x8 (&bqh)[4], const bf16x8 (&bql)[4], const float* __restrict__ sq,
    const int ta, const int tb, const int lhi, float (&ka)[16], float (&kb)[16]) {
  f32x16 a, b;
  #pragma unroll
  for (int i = 0; i < 16; ++i) { a[i] = 0.f; b[i] = 0.f; }
  a = MF(fa.h0, bqh[0], a);  b = MF(fb.h0, bqh[0], b);
  a = MF(fa.h0, bql[0], a);  b = MF(fb.h0, bql[0], b);
  a = MF(fa.l0, bqh[0], a);  b = MF(fb.l0, bqh[0], b);
  a = MF(fa.h1, bqh[1], a);  b = MF(fb.h1, bqh[1], b);
  a = MF(fa.h1, bql[1], a);  b = MF(fb.h1, bql[1], b);
  a = MF(fa.l1, bqh[1], a);  b = MF(fb.l1, bqh[1], b);
  a = MF(fa.h2, bqh[2], a);  b = MF(fb.h2, bqh[2], b);
  a = MF(fa.h2, bql[2], a);  b = MF(fb.h2, bql[2], b);
  a = MF(fa.l2, bqh[2], a);  b = MF(fb.l2, bqh[2], b);
  a = MF(fa.h3, bqh[3], a);  b = MF(fb.h3, bqh[3], b);
  a = MF(fa.h3, bql[3], a);  b = MF(fb.h3, bql[3], b);
  a = MF(fa.l3, bqh[3], a);  b = MF(fb.l3, bqh[3], b);
  const int c0a = ta*32, c0b = tb*32;
  #pragma unroll
  for (int g = 0; g < 4; ++g) {
    const float4 va = *(const float4*)(sq + c0a + g*8 + 4*lhi);
    const float4 vb = *(const float4*)(sq + c0b + g*8 + 4*lhi);
    ka[g*4+0] = fmaf(-2.f, a[g*4+0], va.x);
    ka[g*4+1] = fmaf(-2.f, a[g*4+1], va.y);
    ka[g*4+2] = fmaf(-2.f, a[g*4+2], va.z);
    ka[g*4+3] = fmaf(-2.f, a[g*4+3], va.w);
    kb[g*4+0] = fmaf(-2.f, b[g*4+0], vb.x);
    kb[g*4+1] = fmaf(-2.f, b[g*4+1], vb.y);
    kb[g*4+2] = fmaf(-2.f, b[g*4+2], vb.z);
    kb[g*4+3] = fmaf(-2.f, b[g*4+3], vb.w);
  }
}

#define HIST1(K) { _Pragma("unroll") for (int r = 0; r < 16; ++r) { \
    unsigned x = __float_as_uint(K[r]); x = (x & 0x80000000u) ? ~x : (x | 0x80000000u); \
    atomicAdd(&hist[x >> 24][qcol], 1u); } }
#define HIST2(K) { _Pragma("unroll") for (int r = 0; r < 16; ++r) { \
    unsigned x = __float_as_uint(K[r]); x = (x & 0x80000000u) ? ~x : (x | 0x80000000u); \
    if ((x >> 24) == b1) atomicAdd(&hist[(x >> 16) & 255u][qcol], 1u); } }
#define COLLECT(K, TILE) { _Pragma("unroll") for (int r = 0; r < 16; ++r) { \
    if (K[r] <= bfq) { \
      unsigned x = __float_as_uint(K[r]); x = (x & 0x80000000u) ? ~x : (x | 0x80000000u); \
      const unsigned slot = atomicAdd(&ccnt[qcol], 1u); \
      if (slot < CAP) { \
        const int cidx = (TILE)*32 + (r & 3) + 8*(r >> 2) + 4*lhi; \
        coll[(size_t)q*CAP + slot] = ((unsigned long long)x << 32) | (unsigned)cidx; } } } }

// ---------------- knn: merged bound (1024-subset) + collect, one block per query tile -----
__global__ __launch_bounds__(512) void k_knn(const ushort* __restrict__ pk,
    const float* __restrict__ sq, unsigned long long* __restrict__ coll,
    unsigned* __restrict__ gcnt) {
  __shared__ unsigned hist[256][32];
  __shared__ unsigned part[16][32];
  __shared__ unsigned bin1s[32], below1s[32];
  __shared__ float boundf[32];
  __shared__ unsigned ccnt[32];
  const int tid = threadIdx.x;
  const int wave = tid >> 6, lane = tid & 63;
  const int qcol = lane & 31, lhi = lane >> 5;
  const int qt = blockIdx.x;
  const int q = qt*32 + qcol;

  for (int i = tid; i < 256*32; i += 512) ((unsigned*)hist)[i] = 0u;
  if (tid < 32) ccnt[tid] = 0u;

  bf16x8 bqh[4], bql[4];
  {
    const ushort* tp = pk + (size_t)qt*4096 + (size_t)lane*8;
    #pragma unroll
    for (int ks = 0; ks < 4; ++ks) {
      bqh[ks] = *(const bf16x8*)(tp + ks*1024);
      bql[ks] = *(const bf16x8*)(tp + ks*1024 + 512);
    }
  }
  __syncthreads();

  // phase 1: level-1 hist over subset tiles 0..31 (4 per wave), pairwise interleave
  #pragma unroll 1
  for (int s = 0; s < 4; s += 2) {
    F8 fa, fb;
    ldf(pk, wave*4 + s, lane, fa);
    ldf(pk, wave*4 + s + 1, lane, fb);
    float ka[16], kb[16];
    tile_keys2(fa, fb, bqh, bql, sq, wave*4 + s, wave*4 + s + 1, lhi, ka, kb);
    HIST1(ka)
    HIST1(kb)
  }
  __syncthreads();
  {
    const int qq = tid & 31, j = tid >> 5;
    unsigned ssum = 0;
    #pragma unroll
    for (int i = 0; i < 16; ++i) ssum += hist[j*16 + i][qq];
    part[j][qq] = ssum;
  }
  __syncthreads();
  if (tid < 32) {
    unsigned cum = 0;
    int jj = 0;
    while (jj < 15 && cum + part[jj][tid] < KP1) { cum += part[jj][tid]; ++jj; }
    unsigned c2 = cum, b = 0, fnd = 0;
    #pragma unroll 1
    for (int i = 0; i < 16; ++i) {
      const unsigned nc = c2 + hist[jj*16 + i][tid];
      if (!fnd && nc >= KP1) { b = (unsigned)(jj*16 + i); fnd = 1; break; }
      c2 = nc;
    }
    bin1s[tid] = b; below1s[tid] = c2;
  }
  __syncthreads();
  for (int i = tid; i < 256*32; i += 512) ((unsigned*)hist)[i] = 0u;
  __syncthreads();
  const unsigned b1 = bin1s[qcol];

  // phase 2: level-2 hist within pivot bin (subset tiles 0..31)
  #pragma unroll 1
  for (int s = 0; s < 4; s += 2) {
    F8 fa, fb;
    ldf(pk, wave*4 + s, lane, fa);
    ldf(pk, wave*4 + s + 1, lane, fb);
    float ka[16], kb[16];
    tile_keys2(fa, fb, bqh, bql, sq, wave*4 + s, wave*4 + s + 1, lhi, ka, kb);
    HIST2(ka)
    HIST2(kb)
  }
  __syncthreads();
  {
    const int qq = tid & 31, j = tid >> 5;
    unsigned ssum = 0;
    #pragma unroll
    for (int i = 0; i < 16; ++i) ssum += hist[j*16 + i][qq];
    part[j][qq] = ssum;
  }
  __syncthreads();
  if (tid < 32) {
    unsigned cum = below1s[tid];
    int jj = 0;
    while (jj < 15 && cum + part[jj][tid] < KP1) { cum += part[jj][tid]; ++jj; }
    unsigned c2 = cum, b = 255u, fnd = 0;
    #pragma unroll 1
    for (int i = 0; i < 16; ++i) {
      c2 += hist[jj*16 + i][tid];
      if (!fnd && c2 >= KP1) { b = (unsigned)(jj*16 + i); fnd = 1; }
    }
    const unsigned bu = (bin1s[tid] << 24) | (b << 16) | 0xFFFFu;
    boundf[tid] = __uint_as_float((bu & 0x80000000u) ? (bu & 0x7fffffffu) : ~bu);
  }
  __syncthreads();
  const float bfq = boundf[qcol];

  // phase 3: full scan + collect, 64 tiles/wave, pairwise interleave
  #pragma unroll 1
  for (int s = 0; s < 64; s += 2) {
    F8 fa, fb;
    ldf(pk, wave*64 + s, lane, fa);
    ldf(pk, wave*64 + s + 1, lane, fb);
    float ka[16], kb[16];
    tile_keys2(fa, fb, bqh, bql, sq, wave*64 + s, wave*64 + s + 1, lhi, ka, kb);
    COLLECT(ka, wave*64 + s)
    COLLECT(kb, wave*64 + s + 1)
  }
  __syncthreads();
  if (tid < 32) gcnt[qt*32 + tid] = min(ccnt[tid], (unsigned)CAP);
}

// ---------------- select: one wave per query, exact top-17; fused cnt[to]++ ----------------
__global__ __launch_bounds__(256) void k_select(const unsigned long long* __restrict__ coll,
    const unsigned* __restrict__ gcnt, int* __restrict__ idxout, unsigned* __restrict__ cnt) {
  const int gw = (blockIdx.x*256 + threadIdx.x) >> 6;
  const int lane = threadIdx.x & 63;
  const int m = min((int)gcnt[gw], CAP);
  const unsigned long long* cp = coll + (size_t)gw*CAP;
  unsigned long long a0,a1,a2,a3,a4,a5,a6;
  a0 = (lane       < m) ? cp[lane      ] : ~0ULL;
  a1 = (lane +  64 < m) ? cp[lane +  64] : ~0ULL;
  a2 = (lane + 128 < m) ? cp[lane + 128] : ~0ULL;
  a3 = (lane + 192 < m) ? cp[lane + 192] : ~0ULL;
  a4 = (lane + 256 < m) ? cp[lane + 256] : ~0ULL;
  a5 = (lane + 320 < m) ? cp[lane + 320] : ~0ULL;
  a6 = (lane + 384 < m) ? cp[lane + 384] : ~0ULL;
  #define CS(X,Y) { if (Y < X) { const unsigned long long t_ = X; X = Y; Y = t_; } }
  CS(a0,a1) CS(a2,a3) CS(a4,a5)
  CS(a1,a2) CS(a3,a4) CS(a5,a6)
  CS(a0,a1) CS(a2,a3) CS(a4,a5)
  CS(a1,a2) CS(a3,a4) CS(a5,a6)
  CS(a0,a1) CS(a2,a3) CS(a4,a5)
  CS(a1,a2) CS(a3,a4) CS(a5,a6)
  CS(a0,a1) CS(a2,a3) CS(a4,a5)
  #undef CS
  #pragma unroll
  for (int p = 0; p < KP1; ++p) {
    unsigned long long w = a0;
    #pragma unroll
    for (int d = 1; d < 64; d <<= 1) {
      const unsigned long long o = __shfl_xor(w, d);
      w = o < w ? o : w;
    }
    if (lane == 0) {
      const int ni = (int)(unsigned)(w & 0xffffffffULL);
      idxout[gw*KP1 + p] = ni;
      if (p > 0) atomicAdd(&cnt[ni], 1u);
    }
    if (a0 == w) { a0=a1; a1=a2; a2=a3; a3=a4; a4=a5; a5=a6; a6=~0ULL; }
  }
}

// ---------------- prefix scan of cnt -> offs/pos ----------------
__global__ __launch_bounds__(256) void k_scan(const unsigned* __restrict__ cnt,
    unsigned* __restrict__ offs, unsigned* __restrict__ pos) {
  __shared__ unsigned ps[256];
  const int t = threadIdx.x;
  unsigned s = 0;
  #pragma unroll 4
  for (int j = 0; j < 64; ++j) s += cnt[t*64 + j];
  ps[t] = s;
  __syncthreads();
  for (int d = 1; d < 256; d <<= 1) {
    const unsigned v = (t >= d) ? ps[t-d] : 0u;
    __syncthreads();
    ps[t] += v;
    __syncthreads();
  }
  unsigned run = ps[t] - s;
  #pragma unroll 4
  for (int j = 0; j < 64; ++j) {
    const unsigned c = cnt[t*64 + j];
    offs[t*64 + j] = run; pos[t*64 + j] = run;
    run += c;
  }
}

__global__ __launch_bounds__(256) void k_scatter(const int* __restrict__ idx,
    unsigned* __restrict__ pos, unsigned* __restrict__ sortedE) {
  const int e = blockIdx.x*256 + threadIdx.x;
  const int i = e & (NN-1), k = e >> 14;
  const int to = idx[i*KP1 + k + 1];
  sortedE[atomicAdd(&pos[to], 1u)] = (unsigned)e;
}

// gather-reduce: thread per (node, 16B chunk)
__global__ __launch_bounds__(256) void k_agg(const ushort* __restrict__ y2,
    const unsigned* __restrict__ offs, const unsigned* __restrict__ cnt,
    const unsigned* __restrict__ sortedE,
    const float* __restrict__ s, const float* __restrict__ s2,
    const float* __restrict__ gam, const float* __restrict__ bet, float* __restrict__ agg) {
  __shared__ float scs[64], shs[64];
  const int tid = threadIdx.x;
  if (tid < 64) {
    const float m = s[tid] * (1.f/(float)EE);
    const float v = fmaxf(s2[tid]*(1.f/(float)EE) - m*m, 0.f);
    const float scv = gam[tid]*rsqrtf(v + 1e-5f);
    scs[tid] = scv; shs[tid] = bet[tid] - m*scv;
  }
  __syncthreads();
  const int t = blockIdx.x*256 + tid;
  const int n = t >> 4, c4 = t & 15;
  const unsigned o = offs[n], m = cnt[n];
  const float sc0 = scs[c4*4+0], sc1 = scs[c4*4+1], sc2 = scs[c4*4+2], sc3 = scs[c4*4+3];
  const float sh0 = shs[c4*4+0], sh1 = shs[c4*4+1], sh2 = shs[c4*4+2], sh3 = shs[c4*4+3];
  float a0=0.f, a1=0.f, a2=0.f, a3=0.f;
  for (unsigned j = 0; j < m; ++j) {
    const unsigned e = sortedE[o + j];
    const ushort4 v = *(const ushort4*)(y2 + (size_t)e*64 + c4*4);
    a0 += fmaxf(fmaf(bf2f(v.x), sc0, sh0), 0.f);
    a1 += fmaxf(fmaf(bf2f(v.y), sc1, sh1), 0.f);
    a2 += fmaxf(fmaf(bf2f(v.z), sc2, sh2), 0.f);
    a3 += fmaxf(fmaf(bf2f(v.w), sc3, sh3), 0.f);
  }
  *(float4*)(agg + (size_t)n*64 + c4*4) = make_float4(a0, a1, a2, a3);
}

// ---------------- edge linear-1 (MFMA): y1 = [h[to]|h[frm]] @ W1 + b1, bf16 out ----------------
__global__ __launch_bounds__(256) void k_eA(const ushort* __restrict__ hbh,
    const ushort* __restrict__ hbl, const int* __restrict__ idx,
    const ushort* __restrict__ wp1, const float* __restrict__ b1, ushort* __restrict__ y1) {
  __shared__ ushort wlds[16384];
  __shared__ float b1s[64];
  __shared__ ushort ytr[4][32][40];
  const int tid = threadIdx.x, wave = tid >> 6, lane = tid & 63;
  const int n = lane & 31, lhi = lane >> 5;
  for (int i = tid*8; i < 16384; i += 2048) *(uint4*)(wlds+i) = *(const uint4*)(wp1+i);
  if (tid < 64) b1s[tid] = b1[tid];
  __syncthreads();

  const int tile = blockIdx.x*4 + wave;
  const int e = tile*32 + n;
  const int i_ = e & (NN-1), kk = e >> 14;
  const int to = idx[i_*KP1 + kk + 1];
  const int fr = idx[i_*KP1];

  bf16x8 bh[8], bl[8];
  #pragma unroll
  for (int ks = 0; ks < 4; ++ks) {
    const size_t off = (size_t)to*64 + ks*16 + lhi*8;
    bh[ks] = *(const bf16x8*)(hbh + off);
    bl[ks] = *(const bf16x8*)(hbl + off);
  }
  #pragma unroll
  for (int ks = 0; ks < 4; ++ks) {
    const size_t off = (size_t)fr*64 + ks*16 + lhi*8;
    bh[4+ks] = *(const bf16x8*)(hbh + off);
    bl[4+ks] = *(const bf16x8*)(hbl + off);
  }

  f32x16 aA[2], aB[2];
  #pragma unroll
  for (int i = 0; i < 16; ++i) { aA[0][i]=0.f; aA[1][i]=0.f; aB[0][i]=0.f; aB[1][i]=0.f; }
  #pragma unroll
  for (int mt = 0; mt < 2; ++mt) {
    #pragma unroll
    for (int ks = 0; ks < 8; ++ks) {
      const ushort* wp = wlds + ((mt*8+ks)*2)*512 + lane*8;
      const bf16x8 wh = *(const bf16x8*)wp;
      const bf16x8 wl = *(const bf16x8*)(wp + 512);
      aA[mt] = MF(wh, bh[ks], aA[mt]);
      aB[mt] = MF(wh, bl[ks], aB[mt]);
      aB[mt] = MF(wl, bh[ks], aB[mt]);
    }
  }

  #pragma unroll
  for (int mt = 0; mt < 2; ++mt) {
    #pragma unroll
    for (int g = 0; g < 4; ++g) {
      const int mb = mt*32 + g*8 + lhi*4;
      ushort4 p;
      p.x = f2bf(aA[mt][g*4+0] + aB[mt][g*4+0] + b1s[mb+0]);
      p.y = f2bf(aA[mt][g*4+1] + aB[mt][g*4+1] + b1s[mb+1]);
      p.z = f2bf(aA[mt][g*4+2] + aB[mt][g*4+2] + b1s[mb+2]);
      p.w = f2bf(aA[mt][g*4+3] + aB[mt][g*4+3] + b1s[mb+3]);
      *(ushort4*)(&ytr[wave][n][g*8 + lhi*4]) = p;
    }
    __syncthreads();
    #pragma unroll
    for (int rep = 0; rep < 2; ++rep) {
      const int s = rep*256 + tid;
      const int w = s >> 7, inner = s & 127;
      const int nn = inner >> 2, c8 = inner & 3;
      const bf16x8 v = *(const bf16x8*)(&ytr[w][nn][c8*8]);
      const int tw = blockIdx.x*4 + w;
      *(bf16x8*)(y1 + ((size_t)tw*32 + nn)*64 + mt*32 + c8*8) = v;
    }
    __syncthreads();
  }
}

// ---------------- bf16 column stats over EE rows ----------------
__global__ __launch_bounds__(256) void k_estats(const ushort* __restrict__ y,
    float* __restrict__ s, float* __restrict__ s2) {
  __shared__ float ls[16][64], lq[16][64];
  const int tid = threadIdx.x;
  const int c4 = tid & 15, g = tid >> 4;
  float a0=0,a1=0,a2=0,a3=0,b0=0,b1=0,b2=0,b3=0;
  for (int r = blockIdx.x*16 + g; r < EE; r += 4096) {
    const ushort4 v = *(const ushort4*)(y + (size_t)r*64 + c4*4);
    const float f0 = bf2f(v.x), f1 = bf2f(v.y), f2 = bf2f(v.z), f3 = bf2f(v.w);
    a0 += f0; b0 = fmaf(f0,f0,b0);
    a1 += f1; b1 = fmaf(f1,f1,b1);
    a2 += f2; b2 = fmaf(f2,f2,b2);
    a3 += f3; b3 = fmaf(f3,f3,b3);
  }
  ls[g][c4*4+0]=a0; ls[g][c4*4+1]=a1; ls[g][c4*4+2]=a2; ls[g][c4*4+3]=a3;
  lq[g][c4*4+0]=b0; lq[g][c4*4+1]=b1; lq[g][c4*4+2]=b2; lq[g][c4*4+3]=b3;
  __syncthreads();
  if (tid < 64) {
    float sa = 0.f, sb = 0.f;
    #pragma unroll
    for (int gg = 0; gg < 16; ++gg) { sa += ls[gg][tid]; sb += lq[gg][tid]; }
    atomicAdd(&s[tid], sa); atomicAdd(&s2[tid], sb);
  }
}

// ---------------- edge linear-2 (MFMA): y2 = relu(bn(y1)) @ W2 + b2, bf16 out ----------------
__global__ __launch_bounds__(256) void k_eB(const ushort* __restrict__ y1,
    const float* __restrict__ s, const float* __restrict__ s2,
    const float* __restrict__ gam, const float* __restrict__ bet,
    const ushort* __restrict__ wp2, const float* __restrict__ b2, ushort* __restrict__ y2) {
  __shared__ ushort wlds[8192];
  __shared__ float scs[64], shs[64], b2s[64];
  __shared__ ushort ytr[4][32][40];
  const int tid = threadIdx.x, wave = tid >> 6, lane = tid & 63;
  const int n = lane & 31, lhi = lane >> 5;
  for (int i = tid*8; i < 8192; i += 2048) *(uint4*)(wlds+i) = *(const uint4*)(wp2+i);
  if (tid < 64) {
    const float m = s[tid] * (1.f/(float)EE);
    const float v = fmaxf(s2[tid]*(1.f/(float)EE) - m*m, 0.f);
    const float scv = gam[tid]*rsqrtf(v + 1e-5f);
    scs[tid] = scv; shs[tid] = bet[tid] - m*scv; b2s[tid] = b2[tid];
  }
  __syncthreads();

  const int tile = blockIdx.x*4 + wave;
  const int e = tile*32 + n;

  bf16x8 bh[4], bl[4];
  #pragma unroll
  for (int ks = 0; ks < 4; ++ks) {
    const ushort4 v0 = *(const ushort4*)(y1 + (size_t)e*64 + ks*16 + lhi*8);
    const ushort4 v1 = *(const ushort4*)(y1 + (size_t)e*64 + ks*16 + lhi*8 + 4);
    const int k0 = ks*16 + lhi*8;
    float x[8];
    x[0]=bf2f(v0.x); x[1]=bf2f(v0.y); x[2]=bf2f(v0.z); x[3]=bf2f(v0.w);
    x[4]=bf2f(v1.x); x[5]=bf2f(v1.y); x[6]=bf2f(v1.z); x[7]=bf2f(v1.w);
    #pragma unroll
    for (int j = 0; j < 8; ++j) {
      const float f = fmaxf(fmaf(x[j], scs[k0+j], shs[k0+j]), 0.f);
      const ushort hi = f2bf(f);
      bh[ks][j] = (short)hi;
      bl[ks][j] = (short)f2bf(f - bf2f(hi));
    }
  }

  f32x16 aA[2], aB[2];
  #pragma unroll
  for (int i = 0; i < 16; ++i) { aA[0][i]=0.f; aA[1][i]=0.f; aB[0][i]=0.f; aB[1][i]=0.f; }
  #pragma unroll
  for (int mt = 0; mt < 2; ++mt) {
    #pragma unroll
    for (int ks = 0; ks < 4; ++ks) {
      const ushort* wp = wlds + ((mt*4+ks)*2)*512 + lane*8;
      const bf16x8 wh = *(const bf16x8*)wp;
      const bf16x8 wl = *(const bf16x8*)(wp + 512);
      aA[mt] = MF(wh, bh[ks], aA[mt]);
      aB[mt] = MF(wh, bl[ks], aB[mt]);
      aB[mt] = MF(wl, bh[ks], aB[mt]);
    }
  }

  #pragma unroll
  for (int mt = 0; mt < 2; ++mt) {
    #pragma unroll
    for (int g = 0; g < 4; ++g) {
      const int mb = mt*32 + g*8 + lhi*4;
      ushort4 p;
      p.x = f2bf(aA[mt][g*4+0] + aB[mt][g*4+0] + b2s[mb+0]);
      p.y = f2bf(aA[mt][g*4+1] + aB[mt][g*4+1] + b2s[mb+1]);
      p.z = f2bf(aA[mt][g*4+2] + aB[mt][g*4+2] + b2s[mb+2]);
      p.w = f2bf(aA[mt][g*4+3] + aB[mt][g*4+3] + b2s[mb+3]);
      *(ushort4*)(&ytr[wave][n][g*8 + lhi*4]) = p;
    }
    __syncthreads();
    #pragma unroll
    for (int rep = 0; rep < 2; ++rep) {
      const int ss = rep*256 + tid;
      const int w = ss >> 7, inner = ss & 127;
      const int nn = inner >> 2, c8 = inner & 3;
      const bf16x8 v = *(const bf16x8*)(&ytr[w][nn][c8*8]);
      const int tw = blockIdx.x*4 + w;
      *(bf16x8*)(y2 + ((size_t)tw*32 + nn)*64 + mt*32 + c8*8) = v;
    }
    __syncthreads();
  }
}

// ---------------- fp32 column stats (upd path) ----------------
__global__ __launch_bounds__(256) void k_colstats(const float* __restrict__ x, const int rows,
    float* __restrict__ s, float* __restrict__ s2) {
  __shared__ float ls[4][64], ls2[4][64];
  const int tid = threadIdx.x;
  const int c = tid & 63, g = tid >> 6;
  float a = 0.f, b = 0.f;
  for (int r = blockIdx.x*4 + g; r < rows; r += 1024) {
    const float v = x[(size_t)r*64 + c];
    a += v; b = fmaf(v, v, b);
  }
  ls[g][c] = a; ls2[g][c] = b;
  __syncthreads();
  if (tid < 64) {
    atomicAdd(&s[tid],  ls[0][tid]+ls[1][tid]+ls[2][tid]+ls[3][tid]);
    atomicAdd(&s2[tid], ls2[0][tid]+ls2[1][tid]+ls2[2][tid]+ls2[3][tid]);
  }
}

__device__ __forceinline__ void fmarow(float (&acc)[64], const float (*ws)[64], int kk, float xv) {
  #pragma unroll
  for (int cq = 0; cq < 16; ++cq) {
    const float4 w4 = *(const float4*)&ws[kk][cq*4];
    acc[cq*4]   = fmaf(xv, w4.x, acc[cq*4]);
    acc[cq*4+1] = fmaf(xv, w4.y, acc[cq*4+1]);
    acc[cq*4+2] = fmaf(xv, w4.z, acc[cq*4+2]);
    acc[cq*4+3] = fmaf(xv, w4.w, acc[cq*4+3]);
  }
}

// ---------------- upd linear-1: ubuf = [h | agg] @ W1 + b1 (fp32) ----------------
__global__ __launch_bounds__(256) void k_mlpA_cat(const float* __restrict__ h,
    const float* __restrict__ agg, const float* __restrict__ W1, const float* __restrict__ b1,
    float* __restrict__ y) {
  __shared__ __align__(16) float ws[128][64];
  const int tid = threadIdx.x;
  for (int t = tid; t < 128*64/4; t += 256) ((float4*)ws)[t] = ((const float4*)W1)[t];
  __syncthreads();
  const int n = blockIdx.x*256 + tid;
  float acc[64];
  #pragma unroll
  for (int c = 0; c < 64; ++c) acc[c] = b1[c];
  const float4* xa = (const float4*)(h + (size_t)n*64);
  #pragma unroll 2
  for (int kb = 0; kb < 16; ++kb) {
    const float4 x4 = xa[kb];
    fmarow(acc, ws, kb*4,   x4.x); fmarow(acc, ws, kb*4+1, x4.y);
    fmarow(acc, ws, kb*4+2, x4.z); fmarow(acc, ws, kb*4+3, x4.w);
  }
  const float4* xb = (const float4*)(agg + (size_t)n*64);
  #pragma unroll 2
  for (int kb = 0; kb < 16; ++kb) {
    const float4 x4 = xb[kb];
    fmarow(acc, ws, 64+kb*4,   x4.x); fmarow(acc, ws, 64+kb*4+1, x4.y);
    fmarow(acc, ws, 64+kb*4+2, x4.z); fmarow(acc, ws, 64+kb*4+3, x4.w);
  }
  float4* yo = (float4*)(y + (size_t)n*64);
  #pragma unroll
  for (int q = 0; q < 16; ++q) yo[q] = make_float4(acc[4*q], acc[4*q+1], acc[4*q+2], acc[4*q+3]);
}

// ---------------- upd linear-2 with fused BN+ReLU, in-place (fp32) ----------------
__global__ __launch_bounds__(256) void k_mlpB(float* __restrict__ y,
    const float* __restrict__ s, const float* __restrict__ s2,
    const float* __restrict__ g, const float* __restrict__ be,
    const float* __restrict__ W2, const float* __restrict__ b2, const float invR) {
  __shared__ __align__(16) float ws[64][64];
  __shared__ float sc[64], sh[64];
  const int tid = threadIdx.x;
  for (int t = tid; t < 64*64/4; t += 256) ((float4*)ws)[t] = ((const float4*)W2)[t];
  if (tid < 64) {
    const float m = s[tid]*invR;
    const float v = fmaxf(s2[tid]*invR - m*m, 0.f);
    const float scv = g[tid]*rsqrtf(v + 1e-5f);
    sc[tid] = scv; sh[tid] = be[tid] - m*scv;
  }
  __syncthreads();
  const int e = blockIdx.x*256 + tid;
  float acc[64];
  #pragma unroll
  for (int c = 0; c < 64; ++c) acc[c] = b2[c];
  const float4* yr = (const float4*)(y + (size_t)e*64);
  #pragma unroll 2
  for (int kb = 0; kb < 16; ++kb) {
    const float4 x4 = yr[kb];
    const int k0 = kb*4;
    fmarow(acc, ws, k0,   fmaxf(fmaf(x4.x, sc[k0],   sh[k0]),   0.f));
    fmarow(acc, ws, k0+1, fmaxf(fmaf(x4.y, sc[k0+1], sh[k0+1]), 0.f));
    fmarow(acc, ws, k0+2, fmaxf(fmaf(x4.z, sc[k0+2], sh[k0+2]), 0.f));
    fmarow(acc, ws, k0+3, fmaxf(fmaf(x4.w, sc[k0+3], sh[k0+3]), 0.f));
  }
  float4* yo = (float4*)(y + (size_t)e*64);
  #pragma unroll
  for (int q = 0; q < 16; ++q) yo[q] = make_float4(acc[4*q], acc[4*q+1], acc[4*q+2], acc[4*q+3]);
}

// ---------------- upd final BN+ReLU + residual (layer 3 only) ----------------
__global__ __launch_bounds__(256) void k_updC(const float* __restrict__ y,
    const float* __restrict__ s, const float* __restrict__ s2,
    const float* __restrict__ g, const float* __restrict__ be,
    float* __restrict__ h, const float invR) {
  __shared__ float sc[64], sh[64];
  const int tid = threadIdx.x;
  if (tid < 64) {
    const float m = s[tid]*invR;
    const float v = fmaxf(s2[tid]*invR - m*m, 0.f);
    const float scv = g[tid]*rsqrtf(v + 1e-5f);
    sc[tid] = scv; sh[tid] = be[tid] - m*scv;
  }
  __syncthreads();
  const int t = blockIdx.x*256 + tid;
  const int c = t & 63;
  h[t] += fmaxf(fmaf(y[t], sc[c], sh[c]), 0.f);
}

// ---------------- fused: updC + next-layer prep (layers 0..2) ----------------
__global__ __launch_bounds__(256) void k_updC_prep(const float* __restrict__ y,
    const float* __restrict__ s, const float* __restrict__ s2,
    const float* __restrict__ g, const float* __restrict__ be,
    float* __restrict__ h, const float invR,
    float* __restrict__ sq, ushort* __restrict__ pk,
    ushort* __restrict__ hbh, ushort* __restrict__ hbl) {
  __shared__ float sc[64], sh[64];
  const int tid = threadIdx.x;
  if (tid < 64) {
    const float m = s[tid]*invR;
    const float v = fmaxf(s2[tid]*invR - m*m, 0.f);
    const float scv = g[tid]*rsqrtf(v + 1e-5f);
    sc[tid] = scv; sh[tid] = be[tid] - m*scv;
  }
  __syncthreads();
  const int row = blockIdx.x*256 + tid;
  const int tile = row >> 5, rl = row & 31;
  float4* hp = (float4*)(h + (size_t)row*64);
  const float4* yp = (const float4*)(y + (size_t)row*64);
  float ssum = 0.f;
  #pragma unroll
  for (int q = 0; q < 16; ++q) {
    const float4 yv = yp[q];
    float4 x = hp[q];
    const int k0 = q*4;
    x.x += fmaxf(fmaf(yv.x, sc[k0+0], sh[k0+0]), 0.f);
    x.y += fmaxf(fmaf(yv.y, sc[k0+1], sh[k0+1]), 0.f);
    x.z += fmaxf(fmaf(yv.z, sc[k0+2], sh[k0+2]), 0.f);
    x.w += fmaxf(fmaf(yv.w, sc[k0+3], sh[k0+3]), 0.f);
    hp[q] = x;
    ssum += x.x*x.x + x.y*x.y + x.z*x.z + x.w*x.w;
    ushort4 hi, lo;
    hi.x = f2bf(x.x); lo.x = f2bf(x.x - bf2f(hi.x));
    hi.y = f2bf(x.y); lo.y = f2bf(x.y - bf2f(hi.y));
    hi.z = f2bf(x.z); lo.z = f2bf(x.z - bf2f(hi.z));
    hi.w = f2bf(x.w); lo.w = f2bf(x.w - bf2f(hi.w));
    *(ushort4*)(hbh + (size_t)row*64 + q*4) = hi;
    *(ushort4*)(hbl + (size_t)row*64 + q*4) = lo;
    const int ks = q >> 2, sub = (q >> 1) & 1, e = (q & 1)*4;
    const int lane = rl + 32*sub;
    ushort* base = pk + (size_t)tile*4096 + ks*1024 + (size_t)lane*8 + e;
    *(ushort4*)(base)       = hi;
    *(ushort4*)(base + 512) = lo;
  }
  sq[row] = ssum;
}

// ---------------- out = mean(h) @ predW + predb ----------------
__global__ void k_final(const float* __restrict__ hsum, const float* __restrict__ pW,
                        const float* __restrict__ pb, float* __restrict__ out) {
  const int c = threadIdx.x;
  float v = hsum[c] * (1.f/(float)NN) * pW[c];
  #pragma unroll
  for (int m = 32; m >= 1; m >>= 1) v += __shfl_xor(v, m, 64);
  if (c == 0) out[0] = v + pb[0];
}

extern "C" void kernel_launch(void* const* d_in, const int* in_sizes, int n_in,
                              void* d_out, int out_size, void* d_ws, size_t ws_size,
                              hipStream_t stream) {
  const float* pos   = (const float*)d_in[0];
  const float* linW  = (const float*)d_in[1];
  const float* linb  = (const float*)d_in[2];
  const float* predW = (const float*)d_in[3];
  const float* predb = (const float*)d_in[4];
  const float* mW1 = (const float*)d_in[5];
  const float* mb1 = (const float*)d_in[6];
  const float* mg1 = (const float*)d_in[7];
  const float* mbe1= (const float*)d_in[8];
  const float* mW2 = (const float*)d_in[9];
  const float* mb2 = (const float*)d_in[10];
  const float* mg2 = (const float*)d_in[11];
  const float* mbe2= (const float*)d_in[12];
  const float* uW1 = (const float*)d_in[13];
  const float* ub1 = (const float*)d_in[14];
  const float* ug1 = (const float*)d_in[15];
  const float* ube1= (const float*)d_in[16];
  const float* uW2 = (const float*)d_in[17];
  const float* ub2 = (const float*)d_in[18];
  const float* ug2 = (const float*)d_in[19];
  const float* ube2= (const float*)d_in[20];

  // workspace layout (~81.3 MB)
  float* h     = (float*)d_ws;                    // N*64
  float* sq    = h + (size_t)NN*64;               // N
  float* agg   = sq + NN;                         // N*64
  float* ubuf  = agg + (size_t)NN*64;             // N*64 (4 MB; also scratch below)
  float* stats = ubuf + (size_t)NN*64;            // 640
  int*   idx   = (int*)(stats + 640);             // N*17
  char*  yb    = (char*)(idx + (size_t)NN*KP1);   // 67.3 MB region
  ushort* pk = (ushort*)yb;                                        // 4.19 MB
  unsigned long long* coll = (unsigned long long*)(yb + 4194304);  // 58.72 MB
  ushort* hbh = (ushort*)(yb + 62914560);                          // 2 MB
  ushort* hbl = hbh + (size_t)NN*64;                               // 2 MB
  ushort* y1 = (ushort*)yb;                                        // EE*64 bf16 = 33.5 MB
  ushort* y2 = y1 + (size_t)EE*64;                                 // 33.5 MB
  ushort* wp1 = (ushort*)(yb + 67108864);                          // 128 KB
  ushort* wp2 = wp1 + 4*16384;                                     // 64 KB
  unsigned* cnt     = (unsigned*)ubuf;            // NN
  unsigned* offs    = cnt + NN;                   // NN
  unsigned* pcur    = offs + NN;                  // NN
  unsigned* sortedE = pcur + NN;                  // EE
  unsigned* gcnt    = sortedE + EE;               // NN (k_knn writes all entries; no memset)

  k_lin_in<<<NN*64/256, 256, 0, stream>>>(pos, linW, linb, h);
  k_wprep<<<24, 256, 0, stream>>>(mW1, mW2, wp1, wp2);
  k_prep_all<<<NN/256, 256, 0, stream>>>(h, sq, pk, hbh, hbl);
  for (int l = 0; l < 4; ++l) {
    k_knn<<<NN/32, 512, 0, stream>>>(pk, sq, coll, gcnt);
    hipMemsetAsync(cnt, 0, NN*sizeof(unsigned), stream);
    k_select<<<NN/4, 256, 0, stream>>>(coll, gcnt, idx, cnt);
    hipMemsetAsync(stats, 0, 640*sizeof(float), stream);
    k_scan<<<1, 256, 0, stream>>>(cnt, offs, pcur);
    k_scatter<<<EE/256, 256, 0, stream>>>(idx, pcur, sortedE);
    // edge MLP (MFMA) over E edges
    k_eA<<<EE/32/4, 256, 0, stream>>>(hbh, hbl, idx, wp1 + (size_t)l*16384, mb1 + l*64, y1);
    k_estats<<<256, 256, 0, stream>>>(y1, stats, stats+64);
    k_eB<<<EE/32/4, 256, 0, stream>>>(y1, stats, stats+64, mg1 + l*64, mbe1 + l*64,
                                      wp2 + (size_t)l*8192, mb2 + l*64, y2);
    k_estats<<<256, 256, 0, stream>>>(y2, stats+128, stats+192);
    k_agg<<<NN*16/256, 256, 0, stream>>>(y2, offs, cnt, sortedE, stats+128, stats+192,
                                         mg2 + l*64, mbe2 + l*64, agg);
    // upd MLP over N nodes (fp32)
    k_mlpA_cat<<<NN/256, 256, 0, stream>>>(h, agg, uW1 + l*8192, ub1 + l*64, ubuf);
    k_colstats<<<256, 256, 0, stream>>>(ubuf, NN, stats+256, stats+320);
    k_mlpB<<<NN/256, 256, 0, stream>>>(ubuf, stats+256, stats+320, ug1 + l*64, ube1 + l*64,
                                       uW2 + l*4096, ub2 + l*64, 1.f/(float)NN);
    k_colstats<<<256, 256, 0, stream>>>(ubuf, NN, stats+384, stats+448);
    if (l < 3) {
      k_updC_prep<<<NN/256, 256, 0, stream>>>(ubuf, stats+384, stats+448, ug2 + l*64, ube2 + l*64,
                                              h, 1.f/(float)NN, sq, pk, hbh, hbl);
    } else {
      k_updC<<<NN*64/256, 256, 0, stream>>>(ubuf, stats+384, stats+448, ug2 + l*64, ube2 + l*64,
                                            h, 1.f/(float)NN);
    }
  }
  hipMemsetAsync(stats+512, 0, 128*sizeof(float), stream);
  k_colstats<<<256, 256, 0, stream>>>(h, NN, stats+512, stats+576);
  k_final<<<1, 64, 0, stream>>>(stats+512, predW, predb, (float*)d_out);
}

// Round 16
// 2206.248 us; speedup vs baseline: 2.6952x; 1.0276x over previous
//
#include <hip/hip_runtime.h>

#define NN 16384
#define KP1 17
#define EE (NN*16)
#define CAP 448

typedef short bf16x8 __attribute__((ext_vector_type(8)));
typedef float f32x16 __attribute__((ext_vector_type(16)));

__device__ __forceinline__ ushort f2bf(float f) {
  unsigned u = __float_as_uint(f);
  unsigned r = (u + 0x7fffu + ((u >> 16) & 1u)) >> 16;
  return (ushort)r;
}
__device__ __forceinline__ float bf2f(ushort s) { return __uint_as_float(((unsigned)s) << 16); }

// ---------------- h = pos @ W_in + b ----------------
__global__ __launch_bounds__(256) void k_lin_in(const float* __restrict__ pos,
    const float* __restrict__ W, const float* __restrict__ b, float* __restrict__ h) {
  const int t = blockIdx.x*256 + threadIdx.x;
  const int n = t >> 6, c = t & 63;
  float acc = b[c];
  #pragma unroll
  for (int k = 0; k < 11; ++k) acc = fmaf(pos[n*11+k], W[k*64+c], acc);
  h[t] = acc;
}

// ---------------- fused: sq + pk fragments + bf16 hi/lo row planes ----------------
__global__ __launch_bounds__(256) void k_prep_all(const float* __restrict__ h, float* __restrict__ sq,
    ushort* __restrict__ pk, ushort* __restrict__ hbh, ushort* __restrict__ hbl) {
  const int row = blockIdx.x*256 + threadIdx.x;
  const int tile = row >> 5, rl = row & 31;
  const float4* rp = (const float4*)(h + (size_t)row*64);
  float s = 0.f;
  #pragma unroll
  for (int q = 0; q < 16; ++q) {
    const float4 x = rp[q];
    s += x.x*x.x + x.y*x.y + x.z*x.z + x.w*x.w;
    ushort4 hi, lo;
    hi.x = f2bf(x.x); lo.x = f2bf(x.x - bf2f(hi.x));
    hi.y = f2bf(x.y); lo.y = f2bf(x.y - bf2f(hi.y));
    hi.z = f2bf(x.z); lo.z = f2bf(x.z - bf2f(hi.z));
    hi.w = f2bf(x.w); lo.w = f2bf(x.w - bf2f(hi.w));
    *(ushort4*)(hbh + (size_t)row*64 + q*4) = hi;
    *(ushort4*)(hbl + (size_t)row*64 + q*4) = lo;
    const int ks = q >> 2, sub = (q >> 1) & 1, e = (q & 1)*4;
    const int lane = rl + 32*sub;
    ushort* base = pk + (size_t)tile*4096 + ks*1024 + (size_t)lane*8 + e;
    *(ushort4*)(base)       = hi;
    *(ushort4*)(base + 512) = lo;
  }
  sq[row] = s;
}

// ---------------- one-time weight pack ----------------
__global__ __launch_bounds__(256) void k_wprep(const float* __restrict__ W1all,
    const float* __restrict__ W2all, ushort* __restrict__ wp1, ushort* __restrict__ wp2) {
  const int t = blockIdx.x*256 + threadIdx.x;
  if (t < 4096) {
    const int lane = t & 63, ks = (t>>6)&7, mt = (t>>9)&1, l = t>>10;
    const int m = mt*32 + (lane&31);
    const int k0 = ks*16 + (lane>>5)*8;
    const float* w = W1all + l*8192;
    ushort* dst = wp1 + ((((size_t)l*2 + mt)*8 + ks)*2)*512 + (size_t)lane*8;
    #pragma unroll
    for (int e = 0; e < 8; ++e) {
      const float v = w[(k0+e)*64 + m];
      const ushort hi = f2bf(v);
      dst[e] = hi; dst[512+e] = f2bf(v - bf2f(hi));
    }
  } else if (t < 6144) {
    const int t2 = t - 4096;
    const int lane = t2 & 63, ks = (t2>>6)&3, mt = (t2>>8)&1, l = t2>>9;
    const int m = mt*32 + (lane&31);
    const int k0 = ks*16 + (lane>>5)*8;
    const float* w = W2all + l*4096;
    ushort* dst = wp2 + ((((size_t)l*2 + mt)*4 + ks)*2)*512 + (size_t)lane*8;
    #pragma unroll
    for (int e = 0; e < 8; ++e) {
      const float v = w[(k0+e)*64 + m];
      const ushort hi = f2bf(v);
      dst[e] = hi; dst[512+e] = f2bf(v - bf2f(hi));
    }
  }
}

struct F8 { bf16x8 h0,h1,h2,h3,l0,l1,l2,l3; };

__device__ __forceinline__ void ldf(const ushort* __restrict__ pk, int tile, int lane, F8& f) {
  const ushort* tp = pk + (size_t)tile*4096 + (size_t)lane*8;
  f.h0 = *(const bf16x8*)(tp);
  f.l0 = *(const bf16x8*)(tp + 512);
  f.h1 = *(const bf16x8*)(tp + 1024);
  f.l1 = *(const bf16x8*)(tp + 1536);
  f.h2 = *(const bf16x8*)(tp + 2048);
  f.l2 = *(const bf16x8*)(tp + 2560);
  f.h3 = *(const bf16x8*)(tp + 3072);
  f.l3 = *(const bf16x8*)(tp + 3584);
}

#define MF(A,B,C) __builtin_amdgcn_mfma_f32_32x32x16_bf16(A,B,C,0,0,0)

// two candidate tiles, two INDEPENDENT interleaved MFMA chains (R11/R13-proven shape)
__device__ __forceinline__ void tile_keys2(const F8& fa, const F8& fb,
    const bf16x8 (&bqh)[4], const bf16x8 (&bql)[4], const float* __restrict__ sq,
    const int ta, const int tb, const int lhi, float (&ka)[16], float (&kb)[16]) {
  f32x16 a, b;
  #pragma unroll
  for (int i = 0; i < 16; ++i) { a[i] = 0.f; b[i] = 0.f; }
  a = MF(fa.h0, bqh[0], a);  b = MF(fb.h0, bqh[0], b);
  a = MF(fa.h0, bql[0], a);  b = MF(fb.h0, bql[0], b);
  a = MF(fa.l0, bqh[0], a);  b = MF(fb.l0, bqh[0], b);
  a = MF(fa.h1, bqh[1], a);  b = MF(fb.h1, bqh[1], b);
  a = MF(fa.h1, bql[1], a);  b = MF(fb.h1, bql[1], b);
  a = MF(fa.l1, bqh[1], a);  b = MF(fb.l1, bqh[1], b);
  a = MF(fa.h2, bqh[2], a);  b = MF(fb.h2, bqh[2], b);
  a = MF(fa.h2, bql[2], a);  b = MF(fb.h2, bql[2], b);
  a = MF(fa.l2, bqh[2], a);  b = MF(fb.l2, bqh[2], b);
  a = MF(fa.h3, bqh[3], a);  b = MF(fb.h3, bqh[3], b);
  a = MF(fa.h3, bql[3], a);  b = MF(fb.h3, bql[3], b);
  a = MF(fa.l3, bqh[3], a);  b = MF(fb.l3, bqh[3], b);
  const int c0a = ta*32, c0b = tb*32;
  #pragma unroll
  for (int g = 0; g < 4; ++g) {
    const float4 va = *(const float4*)(sq + c0a + g*8 + 4*lhi);
    const float4 vb = *(const float4*)(sq + c0b + g*8 + 4*lhi);
    ka[g*4+0] = fmaf(-2.f, a[g*4+0], va.x);
    ka[g*4+1] = fmaf(-2.f, a[g*4+1], va.y);
    ka[g*4+2] = fmaf(-2.f, a[g*4+2], va.z);
    ka[g*4+3] = fmaf(-2.f, a[g*4+3], va.w);
    kb[g*4+0] = fmaf(-2.f, b[g*4+0], vb.x);
    kb[g*4+1] = fmaf(-2.f, b[g*4+1], vb.y);
    kb[g*4+2] = fmaf(-2.f, b[g*4+2], vb.z);
    kb[g*4+3] = fmaf(-2.f, b[g*4+3], vb.w);
  }
}

#define HIST1(K) { _Pragma("unroll") for (int r = 0; r < 16; ++r) { \
    unsigned x = __float_as_uint(K[r]); x = (x & 0x80000000u) ? ~x : (x | 0x80000000u); \
    atomicAdd(&hist[x >> 24][qcol], 1u); } }
#define HIST2(K) { _Pragma("unroll") for (int r = 0; r < 16; ++r) { \
    unsigned x = __float_as_uint(K[r]); x = (x & 0x80000000u) ? ~x : (x | 0x80000000u); \
    if ((x >> 24) == b1) atomicAdd(&hist[(x >> 16) & 255u][qcol], 1u); } }
#define COLLECT(K, TILE) { _Pragma("unroll") for (int r = 0; r < 16; ++r) { \
    if (K[r] <= bfq) { \
      unsigned x = __float_as_uint(K[r]); x = (x & 0x80000000u) ? ~x : (x | 0x80000000u); \
      const unsigned slot = atomicAdd(&ccnt[qcol], 1u); \
      if (slot < CAP) { \
        const int cidx = (TILE)*32 + (r & 3) + 8*(r >> 2) + 4*lhi; \
        coll[(size_t)q*CAP + slot] = ((unsigned long long)x << 32) | (unsigned)cidx; } } } }

// ---------------- knn: merged bound (2048-subset) + collect; zeroes cnt for k_select ------
__global__ __launch_bounds__(512) void k_knn(const ushort* __restrict__ pk,
    const float* __restrict__ sq, unsigned long long* __restrict__ coll,
    unsigned* __restrict__ gcnt, unsigned* __restrict__ cnt) {
  __shared__ unsigned hist[256][32];
  __shared__ unsigned part[16][32];
  __shared__ unsigned bin1s[32], below1s[32];
  __shared__ float boundf[32];
  __shared__ unsigned ccnt[32];
  const int tid = threadIdx.x;
  const int wave = tid >> 6, lane = tid & 63;
  const int qcol = lane & 31, lhi = lane >> 5;
  const int qt = blockIdx.x;
  const int q = qt*32 + qcol;

  if (blockIdx.x < 32) cnt[blockIdx.x*512 + tid] = 0u;   // pre-zero in-degree counters

  for (int i = tid; i < 256*32; i += 512) ((unsigned*)hist)[i] = 0u;
  if (tid < 32) ccnt[tid] = 0u;

  bf16x8 bqh[4], bql[4];
  {
    const ushort* tp = pk + (size_t)qt*4096 + (size_t)lane*8;
    #pragma unroll
    for (int ks = 0; ks < 4; ++ks) {
      bqh[ks] = *(const bf16x8*)(tp + ks*1024);
      bql[ks] = *(const bf16x8*)(tp + ks*1024 + 512);
    }
  }
  __syncthreads();

  // phase 1: level-1 hist over subset tiles 0..63 (8 per wave), pairwise interleave
  #pragma unroll 1
  for (int s = 0; s < 8; s += 2) {
    F8 fa, fb;
    ldf(pk, wave*8 + s, lane, fa);
    ldf(pk, wave*8 + s + 1, lane, fb);
    float ka[16], kb[16];
    tile_keys2(fa, fb, bqh, bql, sq, wave*8 + s, wave*8 + s + 1, lhi, ka, kb);
    HIST1(ka)
    HIST1(kb)
  }
  __syncthreads();
  {
    const int qq = tid & 31, j = tid >> 5;
    unsigned ssum = 0;
    #pragma unroll
    for (int i = 0; i < 16; ++i) ssum += hist[j*16 + i][qq];
    part[j][qq] = ssum;
  }
  __syncthreads();
  if (tid < 32) {
    unsigned cum = 0;
    int jj = 0;
    while (jj < 15 && cum + part[jj][tid] < KP1) { cum += part[jj][tid]; ++jj; }
    unsigned c2 = cum, b = 0, fnd = 0;
    #pragma unroll 1
    for (int i = 0; i < 16; ++i) {
      const unsigned nc = c2 + hist[jj*16 + i][tid];
      if (!fnd && nc >= KP1) { b = (unsigned)(jj*16 + i); fnd = 1; break; }
      c2 = nc;
    }
    bin1s[tid] = b; below1s[tid] = c2;
  }
  __syncthreads();
  for (int i = tid; i < 256*32; i += 512) ((unsigned*)hist)[i] = 0u;
  __syncthreads();
  const unsigned b1 = bin1s[qcol];

  // phase 2: level-2 hist within pivot bin
  #pragma unroll 1
  for (int s = 0; s < 8; s += 2) {
    F8 fa, fb;
    ldf(pk, wave*8 + s, lane, fa);
    ldf(pk, wave*8 + s + 1, lane, fb);
    float ka[16], kb[16];
    tile_keys2(fa, fb, bqh, bql, sq, wave*8 + s, wave*8 + s + 1, lhi, ka, kb);
    HIST2(ka)
    HIST2(kb)
  }
  __syncthreads();
  {
    const int qq = tid & 31, j = tid >> 5;
    unsigned ssum = 0;
    #pragma unroll
    for (int i = 0; i < 16; ++i) ssum += hist[j*16 + i][qq];
    part[j][qq] = ssum;
  }
  __syncthreads();
  if (tid < 32) {
    unsigned cum = below1s[tid];
    int jj = 0;
    while (jj < 15 && cum + part[jj][tid] < KP1) { cum += part[jj][tid]; ++jj; }
    unsigned c2 = cum, b = 255u, fnd = 0;
    #pragma unroll 1
    for (int i = 0; i < 16; ++i) {
      c2 += hist[jj*16 + i][tid];
      if (!fnd && c2 >= KP1) { b = (unsigned)(jj*16 + i); fnd = 1; }
    }
    const unsigned bu = (bin1s[tid] << 24) | (b << 16) | 0xFFFFu;
    boundf[tid] = __uint_as_float((bu & 0x80000000u) ? (bu & 0x7fffffffu) : ~bu);
  }
  __syncthreads();
  const float bfq = boundf[qcol];

  // phase 3: full scan + collect, 64 tiles/wave, pairwise interleave
  #pragma unroll 1
  for (int s = 0; s < 64; s += 2) {
    F8 fa, fb;
    ldf(pk, wave*64 + s, lane, fa);
    ldf(pk, wave*64 + s + 1, lane, fb);
    float ka[16], kb[16];
    tile_keys2(fa, fb, bqh, bql, sq, wave*64 + s, wave*64 + s + 1, lhi, ka, kb);
    COLLECT(ka, wave*64 + s)
    COLLECT(kb, wave*64 + s + 1)
  }
  __syncthreads();
  if (tid < 32) gcnt[qt*32 + tid] = min(ccnt[tid], (unsigned)CAP);
}

// ---------------- select: one wave per query, exact top-17; fused cnt[to]++ ----------------
__global__ __launch_bounds__(256) void k_select(const unsigned long long* __restrict__ coll,
    const unsigned* __restrict__ gcnt, int* __restrict__ idxout, unsigned* __restrict__ cnt) {
  const int gw = (blockIdx.x*256 + threadIdx.x) >> 6;
  const int lane = threadIdx.x & 63;
  const int m = min((int)gcnt[gw], CAP);
  const unsigned long long* cp = coll + (size_t)gw*CAP;
  unsigned long long a0,a1,a2,a3,a4,a5,a6;
  a0 = (lane       < m) ? cp[lane      ] : ~0ULL;
  a1 = (lane +  64 < m) ? cp[lane +  64] : ~0ULL;
  a2 = (lane + 128 < m) ? cp[lane + 128] : ~0ULL;
  a3 = (lane + 192 < m) ? cp[lane + 192] : ~0ULL;
  a4 = (lane + 256 < m) ? cp[lane + 256] : ~0ULL;
  a5 = (lane + 320 < m) ? cp[lane + 320] : ~0ULL;
  a6 = (lane + 384 < m) ? cp[lane + 384] : ~0ULL;
  #define CS(X,Y) { if (Y < X) { const unsigned long long t_ = X; X = Y; Y = t_; } }
  CS(a0,a1) CS(a2,a3) CS(a4,a5)
  CS(a1,a2) CS(a3,a4) CS(a5,a6)
  CS(a0,a1) CS(a2,a3) CS(a4,a5)
  CS(a1,a2) CS(a3,a4) CS(a5,a6)
  CS(a0,a1) CS(a2,a3) CS(a4,a5)
  CS(a1,a2) CS(a3,a4) CS(a5,a6)
  CS(a0,a1) CS(a2,a3) CS(a4,a5)
  #undef CS
  #pragma unroll
  for (int p = 0; p < KP1; ++p) {
    unsigned long long w = a0;
    #pragma unroll
    for (int d = 1; d < 64; d <<= 1) {
      const unsigned long long o = __shfl_xor(w, d);
      w = o < w ? o : w;
    }
    if (lane == 0) {
      const int ni = (int)(unsigned)(w & 0xffffffffULL);
      idxout[gw*KP1 + p] = ni;
      if (p > 0) atomicAdd(&cnt[ni], 1u);
    }
    if (a0 == w) { a0=a1; a1=a2; a2=a3; a3=a4; a4=a5; a5=a6; a6=~0ULL; }
  }
}

// ---------------- prefix scan of cnt -> offs/pos ----------------
__global__ __launch_bounds__(256) void k_scan(const unsigned* __restrict__ cnt,
    unsigned* __restrict__ offs, unsigned* __restrict__ pos) {
  __shared__ unsigned ps[256];
  const int t = threadIdx.x;
  unsigned s = 0;
  #pragma unroll 4
  for (int j = 0; j < 64; ++j) s += cnt[t*64 + j];
  ps[t] = s;
  __syncthreads();
  for (int d = 1; d < 256; d <<= 1) {
    const unsigned v = (t >= d) ? ps[t-d] : 0u;
    __syncthreads();
    ps[t] += v;
    __syncthreads();
  }
  unsigned run = ps[t] - s;
  #pragma unroll 4
  for (int j = 0; j < 64; ++j) {
    const unsigned c = cnt[t*64 + j];
    offs[t*64 + j] = run; pos[t*64 + j] = run;
    run += c;
  }
}

// ---------------- scatter edges; block 0 zeroes the per-layer stats slots ----------------
__global__ __launch_bounds__(256) void k_scatter(const int* __restrict__ idx,
    unsigned* __restrict__ pos, unsigned* __restrict__ sortedE, float* __restrict__ stats) {
  const int tid = threadIdx.x;
  if (blockIdx.x == 0) { stats[tid] = 0.f; stats[256 + tid] = 0.f; }  // slots 0..511
  const int e = blockIdx.x*256 + tid;
  const int i = e & (NN-1), k = e >> 14;
  const int to = idx[i*KP1 + k + 1];
  sortedE[atomicAdd(&pos[to], 1u)] = (unsigned)e;
}

// gather-reduce: thread per (node, 16B chunk)
__global__ __launch_bounds__(256) void k_agg(const ushort* __restrict__ y2,
    const unsigned* __restrict__ offs, const unsigned* __restrict__ cnt,
    const unsigned* __restrict__ sortedE,
    const float* __restrict__ s, const float* __restrict__ s2,
    const float* __restrict__ gam, const float* __restrict__ bet, float* __restrict__ agg) {
  __shared__ float scs[64], shs[64];
  const int tid = threadIdx.x;
  if (tid < 64) {
    const float m = s[tid] * (1.f/(float)EE);
    const float v = fmaxf(s2[tid]*(1.f/(float)EE) - m*m, 0.f);
    const float scv = gam[tid]*rsqrtf(v + 1e-5f);
    scs[tid] = scv; shs[tid] = bet[tid] - m*scv;
  }
  __syncthreads();
  const int t = blockIdx.x*256 + tid;
  const int n = t >> 4, c4 = t & 15;
  const unsigned o = offs[n], m = cnt[n];
  const float sc0 = scs[c4*4+0], sc1 = scs[c4*4+1], sc2 = scs[c4*4+2], sc3 = scs[c4*4+3];
  const float sh0 = shs[c4*4+0], sh1 = shs[c4*4+1], sh2 = shs[c4*4+2], sh3 = shs[c4*4+3];
  float a0=0.f, a1=0.f, a2=0.f, a3=0.f;
  for (unsigned j = 0; j < m; ++j) {
    const unsigned e = sortedE[o + j];
    const ushort4 v = *(const ushort4*)(y2 + (size_t)e*64 + c4*4);
    a0 += fmaxf(fmaf(bf2f(v.x), sc0, sh0), 0.f);
    a1 += fmaxf(fmaf(bf2f(v.y), sc1, sh1), 0.f);
    a2 += fmaxf(fmaf(bf2f(v.z), sc2, sh2), 0.f);
    a3 += fmaxf(fmaf(bf2f(v.w), sc3, sh3), 0.f);
  }
  *(float4*)(agg + (size_t)n*64 + c4*4) = make_float4(a0, a1, a2, a3);
}

// ---------------- edge linear-1 (MFMA): y1 = [h[to]|h[frm]] @ W1 + b1, bf16 out ----------------
__global__ __launch_bounds__(256) void k_eA(const ushort* __restrict__ hbh,
    const ushort* __restrict__ hbl, const int* __restrict__ idx,
    const ushort* __restrict__ wp1, const float* __restrict__ b1, ushort* __restrict__ y1) {
  __shared__ ushort wlds[16384];
  __shared__ float b1s[64];
  __shared__ ushort ytr[4][32][40];
  const int tid = threadIdx.x, wave = tid >> 6, lane = tid & 63;
  const int n = lane & 31, lhi = lane >> 5;
  for (int i = tid*8; i < 16384; i += 2048) *(uint4*)(wlds+i) = *(const uint4*)(wp1+i);
  if (tid < 64) b1s[tid] = b1[tid];
  __syncthreads();

  const int tile = blockIdx.x*4 + wave;
  const int e = tile*32 + n;
  const int i_ = e & (NN-1), kk = e >> 14;
  const int to = idx[i_*KP1 + kk + 1];
  const int fr = idx[i_*KP1];

  bf16x8 bh[8], bl[8];
  #pragma unroll
  for (int ks = 0; ks < 4; ++ks) {
    const size_t off = (size_t)to*64 + ks*16 + lhi*8;
    bh[ks] = *(const bf16x8*)(hbh + off);
    bl[ks] = *(const bf16x8*)(hbl + off);
  }
  #pragma unroll
  for (int ks = 0; ks < 4; ++ks) {
    const size_t off = (size_t)fr*64 + ks*16 + lhi*8;
    bh[4+ks] = *(const bf16x8*)(hbh + off);
    bl[4+ks] = *(const bf16x8*)(hbl + off);
  }

  f32x16 aA[2], aB[2];
  #pragma unroll
  for (int i = 0; i < 16; ++i) { aA[0][i]=0.f; aA[1][i]=0.f; aB[0][i]=0.f; aB[1][i]=0.f; }
  #pragma unroll
  for (int mt = 0; mt < 2; ++mt) {
    #pragma unroll
    for (int ks = 0; ks < 8; ++ks) {
      const ushort* wp = wlds + ((mt*8+ks)*2)*512 + lane*8;
      const bf16x8 wh = *(const bf16x8*)wp;
      const bf16x8 wl = *(const bf16x8*)(wp + 512);
      aA[mt] = MF(wh, bh[ks], aA[mt]);
      aB[mt] = MF(wh, bl[ks], aB[mt]);
      aB[mt] = MF(wl, bh[ks], aB[mt]);
    }
  }

  #pragma unroll
  for (int mt = 0; mt < 2; ++mt) {
    #pragma unroll
    for (int g = 0; g < 4; ++g) {
      const int mb = mt*32 + g*8 + lhi*4;
      ushort4 p;
      p.x = f2bf(aA[mt][g*4+0] + aB[mt][g*4+0] + b1s[mb+0]);
      p.y = f2bf(aA[mt][g*4+1] + aB[mt][g*4+1] + b1s[mb+1]);
      p.z = f2bf(aA[mt][g*4+2] + aB[mt][g*4+2] + b1s[mb+2]);
      p.w = f2bf(aA[mt][g*4+3] + aB[mt][g*4+3] + b1s[mb+3]);
      *(ushort4*)(&ytr[wave][n][g*8 + lhi*4]) = p;
    }
    __syncthreads();
    #pragma unroll
    for (int rep = 0; rep < 2; ++rep) {
      const int s = rep*256 + tid;
      const int w = s >> 7, inner = s & 127;
      const int nn = inner >> 2, c8 = inner & 3;
      const bf16x8 v = *(const bf16x8*)(&ytr[w][nn][c8*8]);
      const int tw = blockIdx.x*4 + w;
      *(bf16x8*)(y1 + ((size_t)tw*32 + nn)*64 + mt*32 + c8*8) = v;
    }
    __syncthreads();
  }
}

// ---------------- bf16 column stats over EE rows ----------------
__global__ __launch_bounds__(256) void k_estats(const ushort* __restrict__ y,
    float* __restrict__ s, float* __restrict__ s2) {
  __shared__ float ls[16][64], lq[16][64];
  const int tid = threadIdx.x;
  const int c4 = tid & 15, g = tid >> 4;
  float a0=0,a1=0,a2=0,a3=0,b0=0,b1=0,b2=0,b3=0;
  for (int r = blockIdx.x*16 + g; r < EE; r += 4096) {
    const ushort4 v = *(const ushort4*)(y + (size_t)r*64 + c4*4);
    const float f0 = bf2f(v.x), f1 = bf2f(v.y), f2 = bf2f(v.z), f3 = bf2f(v.w);
    a0 += f0; b0 = fmaf(f0,f0,b0);
    a1 += f1; b1 = fmaf(f1,f1,b1);
    a2 += f2; b2 = fmaf(f2,f2,b2);
    a3 += f3; b3 = fmaf(f3,f3,b3);
  }
  ls[g][c4*4+0]=a0; ls[g][c4*4+1]=a1; ls[g][c4*4+2]=a2; ls[g][c4*4+3]=a3;
  lq[g][c4*4+0]=b0; lq[g][c4*4+1]=b1; lq[g][c4*4+2]=b2; lq[g][c4*4+3]=b3;
  __syncthreads();
  if (tid < 64) {
    float sa = 0.f, sb = 0.f;
    #pragma unroll
    for (int gg = 0; gg < 16; ++gg) { sa += ls[gg][tid]; sb += lq[gg][tid]; }
    atomicAdd(&s[tid], sa); atomicAdd(&s2[tid], sb);
  }
}

// ---------------- edge linear-2 (MFMA): y2 = relu(bn(y1)) @ W2 + b2, bf16 out ----------------
__global__ __launch_bounds__(256) void k_eB(const ushort* __restrict__ y1,
    const float* __restrict__ s, const float* __restrict__ s2,
    const float* __restrict__ gam, const float* __restrict__ bet,
    const ushort* __restrict__ wp2, const float* __restrict__ b2, ushort* __restrict__ y2) {
  __shared__ ushort wlds[8192];
  __shared__ float scs[64], shs[64], b2s[64];
  __shared__ ushort ytr[4][32][40];
  const int tid = threadIdx.x, wave = tid >> 6, lane = tid & 63;
  const int n = lane & 31, lhi = lane >> 5;
  for (int i = tid*8; i < 8192; i += 2048) *(uint4*)(wlds+i) = *(const uint4*)(wp2+i);
  if (tid < 64) {
    const float m = s[tid] * (1.f/(float)EE);
    const float v = fmaxf(s2[tid]*(1.f/(float)EE) - m*m, 0.f);
    const float scv = gam[tid]*rsqrtf(v + 1e-5f);
    scs[tid] = scv; shs[tid] = bet[tid] - m*scv; b2s[tid] = b2[tid];
  }
  __syncthreads();

  const int tile = blockIdx.x*4 + wave;
  const int e = tile*32 + n;

  bf16x8 bh[4], bl[4];
  #pragma unroll
  for (int ks = 0; ks < 4; ++ks) {
    const ushort4 v0 = *(const ushort4*)(y1 + (size_t)e*64 + ks*16 + lhi*8);
    const ushort4 v1 = *(const ushort4*)(y1 + (size_t)e*64 + ks*16 + lhi*8 + 4);
    const int k0 = ks*16 + lhi*8;
    float x[8];
    x[0]=bf2f(v0.x); x[1]=bf2f(v0.y); x[2]=bf2f(v0.z); x[3]=bf2f(v0.w);
    x[4]=bf2f(v1.x); x[5]=bf2f(v1.y); x[6]=bf2f(v1.z); x[7]=bf2f(v1.w);
    #pragma unroll
    for (int j = 0; j < 8; ++j) {
      const float f = fmaxf(fmaf(x[j], scs[k0+j], shs[k0+j]), 0.f);
      const ushort hi = f2bf(f);
      bh[ks][j] = (short)hi;
      bl[ks][j] = (short)f2bf(f - bf2f(hi));
    }
  }

  f32x16 aA[2], aB[2];
  #pragma unroll
  for (int i = 0; i < 16; ++i) { aA[0][i]=0.f; aA[1][i]=0.f; aB[0][i]=0.f; aB[1][i]=0.f; }
  #pragma unroll
  for (int mt = 0; mt < 2; ++mt) {
    #pragma unroll
    for (int ks = 0; ks < 4; ++ks) {
      const ushort* wp = wlds + ((mt*4+ks)*2)*512 + lane*8;
      const bf16x8 wh = *(const bf16x8*)wp;
      const bf16x8 wl = *(const bf16x8*)(wp + 512);
      aA[mt] = MF(wh, bh[ks], aA[mt]);
      aB[mt] = MF(wh, bl[ks], aB[mt]);
      aB[mt] = MF(wl, bh[ks], aB[mt]);
    }
  }

  #pragma unroll
  for (int mt = 0; mt < 2; ++mt) {
    #pragma unroll
    for (int g = 0; g < 4; ++g) {
      const int mb = mt*32 + g*8 + lhi*4;
      ushort4 p;
      p.x = f2bf(aA[mt][g*4+0] + aB[mt][g*4+0] + b2s[mb+0]);
      p.y = f2bf(aA[mt][g*4+1] + aB[mt][g*4+1] + b2s[mb+1]);
      p.z = f2bf(aA[mt][g*4+2] + aB[mt][g*4+2] + b2s[mb+2]);
      p.w = f2bf(aA[mt][g*4+3] + aB[mt][g*4+3] + b2s[mb+3]);
      *(ushort4*)(&ytr[wave][n][g*8 + lhi*4]) = p;
    }
    __syncthreads();
    #pragma unroll
    for (int rep = 0; rep < 2; ++rep) {
      const int ss = rep*256 + tid;
      const int w = ss >> 7, inner = ss & 127;
      const int nn = inner >> 2, c8 = inner & 3;
      const bf16x8 v = *(const bf16x8*)(&ytr[w][nn][c8*8]);
      const int tw = blockIdx.x*4 + w;
      *(bf16x8*)(y2 + ((size_t)tw*32 + nn)*64 + mt*32 + c8*8) = v;
    }
    __syncthreads();
  }
}

// ---------------- fp32 column stats (upd path) ----------------
__global__ __launch_bounds__(256) void k_colstats(const float* __restrict__ x, const int rows,
    float* __restrict__ s, float* __restrict__ s2) {
  __shared__ float ls[4][64], ls2[4][64];
  const int tid = threadIdx.x;
  const int c = tid & 63, g = tid >> 6;
  float a = 0.f, b = 0.f;
  for (int r = blockIdx.x*4 + g; r < rows; r += 1024) {
    const float v = x[(size_t)r*64 + c];
    a += v; b = fmaf(v, v, b);
  }
  ls[g][c] = a; ls2[g][c] = b;
  __syncthreads();
  if (tid < 64) {
    atomicAdd(&s[tid],  ls[0][tid]+ls[1][tid]+ls[2][tid]+ls[3][tid]);
    atomicAdd(&s2[tid], ls2[0][tid]+ls2[1][tid]+ls2[2][tid]+ls2[3][tid]);
  }
}

__device__ __forceinline__ void fmarow(float (&acc)[64], const float (*ws)[64], int kk, float xv) {
  #pragma unroll
  for (int cq = 0; cq < 16; ++cq) {
    const float4 w4 = *(const float4*)&ws[kk][cq*4];
    acc[cq*4]   = fmaf(xv, w4.x, acc[cq*4]);
    acc[cq*4+1] = fmaf(xv, w4.y, acc[cq*4+1]);
    acc[cq*4+2] = fmaf(xv, w4.z, acc[cq*4+2]);
    acc[cq*4+3] = fmaf(xv, w4.w, acc[cq*4+3]);
  }
}

// ---------------- upd linear-1: ubuf = [h | agg] @ W1 + b1 (fp32) ----------------
__global__ __launch_bounds__(256) void k_mlpA_cat(const float* __restrict__ h,
    const float* __restrict__ agg, const float* __restrict__ W1, const float* __restrict__ b1,
    float* __restrict__ y) {
  __shared__ __align__(16) float ws[128][64];
  const int tid = threadIdx.x;
  for (int t = tid; t < 128*64/4; t += 256) ((float4*)ws)[t] = ((const float4*)W1)[t];
  __syncthreads();
  const int n = blockIdx.x*256 + tid;
  float acc[64];
  #pragma unroll
  for (int c = 0; c < 64; ++c) acc[c] = b1[c];
  const float4* xa = (const float4*)(h + (size_t)n*64);
  #pragma unroll 2
  for (int kb = 0; kb < 16; ++kb) {
    const float4 x4 = xa[kb];
    fmarow(acc, ws, kb*4,   x4.x); fmarow(acc, ws, kb*4+1, x4.y);
    fmarow(acc, ws, kb*4+2, x4.z); fmarow(acc, ws, kb*4+3, x4.w);
  }
  const float4* xb = (const float4*)(agg + (size_t)n*64);
  #pragma unroll 2
  for (int kb = 0; kb < 16; ++kb) {
    const float4 x4 = xb[kb];
    fmarow(acc, ws, 64+kb*4,   x4.x); fmarow(acc, ws, 64+kb*4+1, x4.y);
    fmarow(acc, ws, 64+kb*4+2, x4.z); fmarow(acc, ws, 64+kb*4+3, x4.w);
  }
  float4* yo = (float4*)(y + (size_t)n*64);
  #pragma unroll
  for (int q = 0; q < 16; ++q) yo[q] = make_float4(acc[4*q], acc[4*q+1], acc[4*q+2], acc[4*q+3]);
}

// ---------------- upd linear-2 with fused BN+ReLU, in-place (fp32) ----------------
__global__ __launch_bounds__(256) void k_mlpB(float* __restrict__ y,
    const float* __restrict__ s, const float* __restrict__ s2,
    const float* __restrict__ g, const float* __restrict__ be,
    const float* __restrict__ W2, const float* __restrict__ b2, const float invR) {
  __shared__ __align__(16) float ws[64][64];
  __shared__ float sc[64], sh[64];
  const int tid = threadIdx.x;
  for (int t = tid; t < 64*64/4; t += 256) ((float4*)ws)[t] = ((const float4*)W2)[t];
  if (tid < 64) {
    const float m = s[tid]*invR;
    const float v = fmaxf(s2[tid]*invR - m*m, 0.f);
    const float scv = g[tid]*rsqrtf(v + 1e-5f);
    sc[tid] = scv; sh[tid] = be[tid] - m*scv;
  }
  __syncthreads();
  const int e = blockIdx.x*256 + tid;
  float acc[64];
  #pragma unroll
  for (int c = 0; c < 64; ++c) acc[c] = b2[c];
  const float4* yr = (const float4*)(y + (size_t)e*64);
  #pragma unroll 2
  for (int kb = 0; kb < 16; ++kb) {
    const float4 x4 = yr[kb];
    const int k0 = kb*4;
    fmarow(acc, ws, k0,   fmaxf(fmaf(x4.x, sc[k0],   sh[k0]),   0.f));
    fmarow(acc, ws, k0+1, fmaxf(fmaf(x4.y, sc[k0+1], sh[k0+1]), 0.f));
    fmarow(acc, ws, k0+2, fmaxf(fmaf(x4.z, sc[k0+2], sh[k0+2]), 0.f));
    fmarow(acc, ws, k0+3, fmaxf(fmaf(x4.w, sc[k0+3], sh[k0+3]), 0.f));
  }
  float4* yo = (float4*)(y + (size_t)e*64);
  #pragma unroll
  for (int q = 0; q < 16; ++q) yo[q] = make_float4(acc[4*q], acc[4*q+1], acc[4*q+2], acc[4*q+3]);
}

// ---------------- upd final BN+ReLU + residual (layer 3 only) ----------------
__global__ __launch_bounds__(256) void k_updC(const float* __restrict__ y,
    const float* __restrict__ s, const float* __restrict__ s2,
    const float* __restrict__ g, const float* __restrict__ be,
    float* __restrict__ h, const float invR) {
  __shared__ float sc[64], sh[64];
  const int tid = threadIdx.x;
  if (tid < 64) {
    const float m = s[tid]*invR;
    const float v = fmaxf(s2[tid]*invR - m*m, 0.f);
    const float scv = g[tid]*rsqrtf(v + 1e-5f);
    sc[tid] = scv; sh[tid] = be[tid] - m*scv;
  }
  __syncthreads();
  const int t = blockIdx.x*256 + tid;
  const int c = t & 63;
  h[t] += fmaxf(fmaf(y[t], sc[c], sh[c]), 0.f);
}

// ---------------- fused: updC + next-layer prep (layers 0..2) ----------------
__global__ __launch_bounds__(256) void k_updC_prep(const float* __restrict__ y,
    const float* __restrict__ s, const float* __restrict__ s2,
    const float* __restrict__ g, const float* __restrict__ be,
    float* __restrict__ h, const float invR,
    float* __restrict__ sq, ushort* __restrict__ pk,
    ushort* __restrict__ hbh, ushort* __restrict__ hbl) {
  __shared__ float sc[64], sh[64];
  const int tid = threadIdx.x;
  if (tid < 64) {
    const float m = s[tid]*invR;
    const float v = fmaxf(s2[tid]*invR - m*m, 0.f);
    const float scv = g[tid]*rsqrtf(v + 1e-5f);
    sc[tid] = scv; sh[tid] = be[tid] - m*scv;
  }
  __syncthreads();
  const int row = blockIdx.x*256 + tid;
  const int tile = row >> 5, rl = row & 31;
  float4* hp = (float4*)(h + (size_t)row*64);
  const float4* yp = (const float4*)(y + (size_t)row*64);
  float ssum = 0.f;
  #pragma unroll
  for (int q = 0; q < 16; ++q) {
    const float4 yv = yp[q];
    float4 x = hp[q];
    const int k0 = q*4;
    x.x += fmaxf(fmaf(yv.x, sc[k0+0], sh[k0+0]), 0.f);
    x.y += fmaxf(fmaf(yv.y, sc[k0+1], sh[k0+1]), 0.f);
    x.z += fmaxf(fmaf(yv.z, sc[k0+2], sh[k0+2]), 0.f);
    x.w += fmaxf(fmaf(yv.w, sc[k0+3], sh[k0+3]), 0.f);
    hp[q] = x;
    ssum += x.x*x.x + x.y*x.y + x.z*x.z + x.w*x.w;
    ushort4 hi, lo;
    hi.x = f2bf(x.x); lo.x = f2bf(x.x - bf2f(hi.x));
    hi.y = f2bf(x.y); lo.y = f2bf(x.y - bf2f(hi.y));
    hi.z = f2bf(x.z); lo.z = f2bf(x.z - bf2f(hi.z));
    hi.w = f2bf(x.w); lo.w = f2bf(x.w - bf2f(hi.w));
    *(ushort4*)(hbh + (size_t)row*64 + q*4) = hi;
    *(ushort4*)(hbl + (size_t)row*64 + q*4) = lo;
    const int ks = q >> 2, sub = (q >> 1) & 1, e = (q & 1)*4;
    const int lane = rl + 32*sub;
    ushort* base = pk + (size_t)tile*4096 + ks*1024 + (size_t)lane*8 + e;
    *(ushort4*)(base)       = hi;
    *(ushort4*)(base + 512) = lo;
  }
  sq[row] = ssum;
}

// ---------------- out = mean(h) @ predW + predb ----------------
__global__ void k_final(const float* __restrict__ hsum, const float* __restrict__ pW,
                        const float* __restrict__ pb, float* __restrict__ out) {
  const int c = threadIdx.x;
  float v = hsum[c] * (1.f/(float)NN) * pW[c];
  #pragma unroll
  for (int m = 32; m >= 1; m >>= 1) v += __shfl_xor(v, m, 64);
  if (c == 0) out[0] = v + pb[0];
}

extern "C" void kernel_launch(void* const* d_in, const int* in_sizes, int n_in,
                              void* d_out, int out_size, void* d_ws, size_t ws_size,
                              hipStream_t stream) {
  const float* pos   = (const float*)d_in[0];
  const float* linW  = (const float*)d_in[1];
  const float* linb  = (const float*)d_in[2];
  const float* predW = (const float*)d_in[3];
  const float* predb = (const float*)d_in[4];
  const float* mW1 = (const float*)d_in[5];
  const float* mb1 = (const float*)d_in[6];
  const float* mg1 = (const float*)d_in[7];
  const float* mbe1= (const float*)d_in[8];
  const float* mW2 = (const float*)d_in[9];
  const float* mb2 = (const float*)d_in[10];
  const float* mg2 = (const float*)d_in[11];
  const float* mbe2= (const float*)d_in[12];
  const float* uW1 = (const float*)d_in[13];
  const float* ub1 = (const float*)d_in[14];
  const float* ug1 = (const float*)d_in[15];
  const float* ube1= (const float*)d_in[16];
  const float* uW2 = (const float*)d_in[17];
  const float* ub2 = (const float*)d_in[18];
  const float* ug2 = (const float*)d_in[19];
  const float* ube2= (const float*)d_in[20];

  // workspace layout (~81.3 MB)
  float* h     = (float*)d_ws;                    // N*64
  float* sq    = h + (size_t)NN*64;               // N
  float* agg   = sq + NN;                         // N*64
  float* ubuf  = agg + (size_t)NN*64;             // N*64 (4 MB; also scratch below)
  float* stats = ubuf + (size_t)NN*64;            // 640
  int*   idx   = (int*)(stats + 640);             // N*17
  char*  yb    = (char*)(idx + (size_t)NN*KP1);   // 67.3 MB region
  ushort* pk = (ushort*)yb;                                        // 4.19 MB
  unsigned long long* coll = (unsigned long long*)(yb + 4194304);  // 58.72 MB
  ushort* hbh = (ushort*)(yb + 62914560);                          // 2 MB
  ushort* hbl = hbh + (size_t)NN*64;                               // 2 MB
  ushort* y1 = (ushort*)yb;                                        // EE*64 bf16 = 33.5 MB
  ushort* y2 = y1 + (size_t)EE*64;                                 // 33.5 MB
  ushort* wp1 = (ushort*)(yb + 67108864);                          // 128 KB
  ushort* wp2 = wp1 + 4*16384;                                     // 64 KB
  unsigned* cnt     = (unsigned*)ubuf;            // NN
  unsigned* offs    = cnt + NN;                   // NN
  unsigned* pcur    = offs + NN;                  // NN
  unsigned* sortedE = pcur + NN;                  // EE
  unsigned* gcnt    = sortedE + EE;               // NN (k_knn writes all entries; no memset)

  k_lin_in<<<NN*64/256, 256, 0, stream>>>(pos, linW, linb, h);
  k_wprep<<<24, 256, 0, stream>>>(mW1, mW2, wp1, wp2);
  k_prep_all<<<NN/256, 256, 0, stream>>>(h, sq, pk, hbh, hbl);
  for (int l = 0; l < 4; ++l) {
    k_knn<<<NN/32, 512, 0, stream>>>(pk, sq, coll, gcnt, cnt);
    k_select<<<NN/4, 256, 0, stream>>>(coll, gcnt, idx, cnt);
    k_scan<<<1, 256, 0, stream>>>(cnt, offs, pcur);
    k_scatter<<<EE/256, 256, 0, stream>>>(idx, pcur, sortedE, stats);
    // edge MLP (MFMA) over E edges
    k_eA<<<EE/32/4, 256, 0, stream>>>(hbh, hbl, idx, wp1 + (size_t)l*16384, mb1 + l*64, y1);
    k_estats<<<256, 256, 0, stream>>>(y1, stats, stats+64);
    k_eB<<<EE/32/4, 256, 0, stream>>>(y1, stats, stats+64, mg1 + l*64, mbe1 + l*64,
                                      wp2 + (size_t)l*8192, mb2 + l*64, y2);
    k_estats<<<256, 256, 0, stream>>>(y2, stats+128, stats+192);
    k_agg<<<NN*16/256, 256, 0, stream>>>(y2, offs, cnt, sortedE, stats+128, stats+192,
                                         mg2 + l*64, mbe2 + l*64, agg);
    // upd MLP over N nodes (fp32)
    k_mlpA_cat<<<NN/256, 256, 0, stream>>>(h, agg, uW1 + l*8192, ub1 + l*64, ubuf);
    k_colstats<<<256, 256, 0, stream>>>(ubuf, NN, stats+256, stats+320);
    k_mlpB<<<NN/256, 256, 0, stream>>>(ubuf, stats+256, stats+320, ug1 + l*64, ube1 + l*64,
                                       uW2 + l*4096, ub2 + l*64, 1.f/(float)NN);
    k_colstats<<<256, 256, 0, stream>>>(ubuf, NN, stats+384, stats+448);
    if (l < 3) {
      k_updC_prep<<<NN/256, 256, 0, stream>>>(ubuf, stats+384, stats+448, ug2 + l*64, ube2 + l*64,
                                              h, 1.f/(float)NN, sq, pk, hbh, hbl);
    } else {
      k_updC<<<NN*64/256, 256, 0, stream>>>(ubuf, stats+384, stats+448, ug2 + l*64, ube2 + l*64,
                                            h, 1.f/(float)NN);
    }
  }
  hipMemsetAsync(stats+512, 0, 128*sizeof(float), stream);
  k_colstats<<<256, 256, 0, stream>>>(h, NN, stats+512, stats+576);
  k_final<<<1, 64, 0, stream>>>(stats+512, predW, predb, (float*)d_out);
}